// Round 2
// baseline (849.735 us; speedup 1.0000x reference)
//
#include <hip/hip_runtime.h>
#include <cstdint>

typedef unsigned short u16;
typedef __attribute__((ext_vector_type(8))) __bf16 bf16x8;
typedef __attribute__((ext_vector_type(4))) float f32x4;

__device__ __forceinline__ u16 f2bf(float f) {
    union { float f; uint32_t u; } v; v.f = f;
    uint32_t u = v.u;
    uint32_t r = (u + 0x7fffu + ((u >> 16) & 1u)) >> 16;
    return (u16)r;
}
__device__ __forceinline__ float bf2f(u16 h) {
    union { uint32_t u; float f; } v; v.u = ((uint32_t)h) << 16;
    return v.f;
}

// async global->LDS 16B per lane; LDS dest must be wave-uniform base + lane*16
__device__ __forceinline__ void ld_lds16(const u16* g, u16* l) {
    __builtin_amdgcn_global_load_lds(
        (const __attribute__((address_space(1))) uint32_t*)g,
        (__attribute__((address_space(3))) uint32_t*)l, 16, 0, 0);
}

// ---------------------------------------------------------------- prep ------
__global__ __launch_bounds__(256) void prep(
    const float* __restrict__ proj_w, const float* __restrict__ proj_g,
    const float* __restrict__ proj_b, const float* __restrict__ vp2_w,
    const float* __restrict__ pw1_w, const float* __restrict__ pw2_w,
    const float* __restrict__ dw_w,
    u16* __restrict__ w1p, u16* __restrict__ w2, u16* __restrict__ w3,
    u16* __restrict__ w4, float* __restrict__ gp, float2* __restrict__ dwp)
{
    int i = blockIdx.x * 256 + threadIdx.x;
    if (i < 245760) {                 // w1p: 640x384, rows >=576 zero
        int o = i / 384, k = i - o * 384;
        w1p[i] = (o < 576) ? f2bf(proj_w[o * 386 + k]) : (u16)0;
        return;
    }
    i -= 245760;
    if (i < 73728) { w2[i] = f2bf(vp2_w[i]); return; }   // 384x192
    i -= 73728;
    if (i < 589824) { w3[i] = f2bf(pw1_w[i]); return; }  // 1536x384
    i -= 589824;
    if (i < 589824) { w4[i] = f2bf(pw2_w[i]); return; }  // 384x1536
    i -= 589824;
    if (i < 2560) {                   // gp: [g1p|b1p|w1x|w1y] each 640 fp32
        int which = i / 640, o = i - which * 640;
        float v = 0.f;
        if (o < 576) {
            v = (which == 0) ? proj_g[o] : (which == 1) ? proj_b[o]
                : (which == 2) ? proj_w[o * 386 + 384] : proj_w[o * 386 + 385];
        }
        gp[i] = v; return;
    }
    i -= 2560;
    if (i < 4800) {                   // dwp TRANSPOSED: [tap 0..24][cp 0..191]
        int tap = i / 192, cp = i - tap * 192;
        dwp[i] = make_float2(dw_w[(2 * cp) * 25 + tap], dw_w[(2 * cp + 1) * 25 + tap]);
    }
}

// ------------------------------------------------- NCHW fp32 -> NHWC bf16 ---
__global__ __launch_bounds__(256) void transpose_x(const float* __restrict__ x,
                                                   u16* __restrict__ xt)
{
    __shared__ float tile[64][65];
    int b = blockIdx.x, n0 = blockIdx.y * 64, c0 = blockIdx.z * 64;
    int t = threadIdx.x;
    int jj = t & 63, i0 = t >> 6;
    #pragma unroll
    for (int r = 0; r < 16; r++) {
        int ci = r * 4 + i0;
        tile[ci][jj] = x[((size_t)b * 384 + c0 + ci) * 4096 + n0 + jj];
    }
    __syncthreads();
    #pragma unroll
    for (int r = 0; r < 16; r++) {
        int ni = r * 4 + i0;
        xt[(size_t)(b * 4096 + n0 + ni) * 384 + c0 + jj] = f2bf(tile[jj][ni]);
    }
}

// ------------------------------------------------- NHWC bf16 -> NCHW fp32 ---
__global__ __launch_bounds__(256) void transpose_out(const u16* __restrict__ zf,
                                                     float* __restrict__ out)
{
    __shared__ float tile[64][65];
    int b = blockIdx.x, n0 = blockIdx.y * 64, c0 = blockIdx.z * 64;
    int t = threadIdx.x;
    int jj = t & 63, i0 = t >> 6;
    #pragma unroll
    for (int r = 0; r < 16; r++) {
        int ni = r * 4 + i0;
        tile[ni][jj] = bf2f(zf[(size_t)(b * 4096 + n0 + ni) * 384 + c0 + jj]);
    }
    __syncthreads();
    #pragma unroll
    for (int r = 0; r < 16; r++) {
        int ci = r * 4 + i0;
        out[((size_t)b * 384 + c0 + ci) * 4096 + n0 + jj] = tile[jj][ci];
    }
}

// --------------------------------------------------------------- GEMM -------
// Out[pix][o] = epilogue( sum_k A[pix][k] * W[o][k] )   (both k-contiguous)
// v3: A staged via 3-buffer global_load_lds pipeline (counted vmcnt(6), one
// barrier/iter, distance-2 prefetch). B (weights, <=1.2 MB, L2-resident) is
// NOT staged in LDS: fragments load straight into registers with a 1-iter
// software pipeline (named double set, unroll-2). LDS = 24 KB -> 6 blocks/CU.
// ds_reads of the current buffer are issued BEFORE this iteration's DMA /
// global loads so any conservative compiler wait covers only >=1-iter-old ops.
template <int MODE>
__global__ __launch_bounds__(256) void gemm_nhwc(
    const u16* __restrict__ A, const u16* __restrict__ W,
    u16* __restrict__ out, int K, int Osz, int nOT,
    const float* __restrict__ g, const float* __restrict__ bb,
    const float* __restrict__ w1x, const float* __restrict__ w1y,
    const u16* __restrict__ res, const float* __restrict__ sc,
    const float* __restrict__ rnd)
{
    constexpr int BK = 32;
    __shared__ u16 sA[3][128 * BK];
    const int tid = threadIdx.x;
    const int lane = tid & 63;
    const int wv = tid >> 6;
    const int wm = (wv >> 1) * 64;
    const int wn = (wv & 1) * 64;

    // bijective XCD chunking: nwg divisible by 8 in all launches
    const int nwg = gridDim.x;
    const int q8 = nwg >> 3;
    const int b1 = (blockIdx.x & 7) * q8 + (blockIdx.x >> 3);
    const int mt = b1 / nOT;
    const int ot = b1 - mt * nOT;
    const int m0 = mt * 128;
    const int o0 = ot * 128;

    const int q = lane >> 4;
    const int mr = lane & 15;
    // swizzled k-slot this lane READS from LDS A: slot = q ^ ((row>>1)&3)
    const int ks = (q ^ ((mr >> 1) & 3)) * 8;

    const int tq = tid >> 2;          // staging row 0..63 (+64 for 2nd group)
    const int sl = tid & 3;           // linear LDS slot (dest is lane-linear)
    const int tk = (sl ^ ((tq >> 1) & 3)) * 8;   // swizzled GLOBAL k-chunk
    const size_t ga0 = (size_t)(m0 + tq) * K + tk;
    const size_t ga1 = (size_t)(m0 + 64 + tq) * K + tk;
    const int lo0 = tq * BK + sl * 8;
    const int lo1 = (64 + tq) * BK + sl * 8;

    // B row pointers (k-contiguous); this lane's frag column base is q*8
    const u16* wr0 = W + (size_t)(o0 + wn +  0 + mr) * K + q * 8;
    const u16* wr1 = W + (size_t)(o0 + wn + 16 + mr) * K + q * 8;
    const u16* wr2 = W + (size_t)(o0 + wn + 32 + mr) * K + q * 8;
    const u16* wr3 = W + (size_t)(o0 + wn + 48 + mr) * K + q * 8;

    f32x4 acc[4][4] = {};
    const int nIter = K >> 5;         // even (6/12/12/48) for all launches

    // prologue: A tiles 0,1 in flight (2 DMA each); B frags for tile 0 in regs
    ld_lds16(A + ga0, &sA[0][lo0]);
    ld_lds16(A + ga1, &sA[0][lo1]);
    ld_lds16(A + ga0 + BK, &sA[1][lo0]);
    ld_lds16(A + ga1 + BK, &sA[1][lo1]);
    bf16x8 bX0 = *(const bf16x8*)(wr0);
    bf16x8 bX1 = *(const bf16x8*)(wr1);
    bf16x8 bX2 = *(const bf16x8*)(wr2);
    bf16x8 bX3 = *(const bf16x8*)(wr3);
    bf16x8 bY0, bY1, bY2, bY3;

    int buf = 0;

    // vmcnt(6) is safe every iter: newer-than-A(t) = A(t+1):2 + B(t):4 = 6
    // (prologue: newer-than-A(0) = A(1):2 + B(0):4 = 6).
#define GEMM_ITER(T, C0, C1, C2, C3, N0, N1, N2, N3)                         \
    {                                                                        \
        asm volatile("s_waitcnt vmcnt(6)" ::: "memory");                     \
        __builtin_amdgcn_s_barrier();                                        \
        __builtin_amdgcn_sched_barrier(0);                                   \
        bf16x8 af0 = *(const bf16x8*)&sA[buf][(wm +  0 + mr) * BK + ks];     \
        bf16x8 af1 = *(const bf16x8*)&sA[buf][(wm + 16 + mr) * BK + ks];     \
        bf16x8 af2 = *(const bf16x8*)&sA[buf][(wm + 32 + mr) * BK + ks];     \
        bf16x8 af3 = *(const bf16x8*)&sA[buf][(wm + 48 + mr) * BK + ks];     \
        if ((T) + 2 < nIter) {        /* prefetch A tile T+2 (distance 2) */ \
            int nb = buf + 2; if (nb >= 3) nb -= 3;                          \
            size_t ko = (size_t)((T) + 2) * BK;                              \
            ld_lds16(A + ga0 + ko, &sA[nb][lo0]);                            \
            ld_lds16(A + ga1 + ko, &sA[nb][lo1]);                            \
        }                                                                    \
        if ((T) + 1 < nIter) {        /* pipeline B frags for tile T+1 */    \
            int kb = ((T) + 1) * BK;                                         \
            N0 = *(const bf16x8*)(wr0 + kb);                                 \
            N1 = *(const bf16x8*)(wr1 + kb);                                 \
            N2 = *(const bf16x8*)(wr2 + kb);                                 \
            N3 = *(const bf16x8*)(wr3 + kb);                                 \
        }                                                                    \
        __builtin_amdgcn_s_setprio(1);                                       \
        acc[0][0] = __builtin_amdgcn_mfma_f32_16x16x32_bf16(af0, C0, acc[0][0], 0, 0, 0); \
        acc[0][1] = __builtin_amdgcn_mfma_f32_16x16x32_bf16(af0, C1, acc[0][1], 0, 0, 0); \
        acc[0][2] = __builtin_amdgcn_mfma_f32_16x16x32_bf16(af0, C2, acc[0][2], 0, 0, 0); \
        acc[0][3] = __builtin_amdgcn_mfma_f32_16x16x32_bf16(af0, C3, acc[0][3], 0, 0, 0); \
        acc[1][0] = __builtin_amdgcn_mfma_f32_16x16x32_bf16(af1, C0, acc[1][0], 0, 0, 0); \
        acc[1][1] = __builtin_amdgcn_mfma_f32_16x16x32_bf16(af1, C1, acc[1][1], 0, 0, 0); \
        acc[1][2] = __builtin_amdgcn_mfma_f32_16x16x32_bf16(af1, C2, acc[1][2], 0, 0, 0); \
        acc[1][3] = __builtin_amdgcn_mfma_f32_16x16x32_bf16(af1, C3, acc[1][3], 0, 0, 0); \
        acc[2][0] = __builtin_amdgcn_mfma_f32_16x16x32_bf16(af2, C0, acc[2][0], 0, 0, 0); \
        acc[2][1] = __builtin_amdgcn_mfma_f32_16x16x32_bf16(af2, C1, acc[2][1], 0, 0, 0); \
        acc[2][2] = __builtin_amdgcn_mfma_f32_16x16x32_bf16(af2, C2, acc[2][2], 0, 0, 0); \
        acc[2][3] = __builtin_amdgcn_mfma_f32_16x16x32_bf16(af2, C3, acc[2][3], 0, 0, 0); \
        acc[3][0] = __builtin_amdgcn_mfma_f32_16x16x32_bf16(af3, C0, acc[3][0], 0, 0, 0); \
        acc[3][1] = __builtin_amdgcn_mfma_f32_16x16x32_bf16(af3, C1, acc[3][1], 0, 0, 0); \
        acc[3][2] = __builtin_amdgcn_mfma_f32_16x16x32_bf16(af3, C2, acc[3][2], 0, 0, 0); \
        acc[3][3] = __builtin_amdgcn_mfma_f32_16x16x32_bf16(af3, C3, acc[3][3], 0, 0, 0); \
        __builtin_amdgcn_s_setprio(0);                                       \
        buf++; if (buf == 3) buf = 0;                                        \
    }

    for (int t = 0; t < nIter; t += 2) {
        GEMM_ITER(t,     bX0, bX1, bX2, bX3, bY0, bY1, bY2, bY3)
        GEMM_ITER(t + 1, bY0, bY1, bY2, bY3, bX0, bX1, bX2, bX3)
    }
#undef GEMM_ITER

    float E = 0.f, offx = 0.f, offy = 0.f, rz = 0.f;
    if constexpr (MODE == 1) {
        E = expf(sc[0]);
        int bimg = m0 >> 12;
        offx = rnd[bimg * 2 + 0];
        offy = rnd[bimg * 2 + 1];
    }
    if constexpr (MODE == 2 || MODE == 4) rz = sc[0];

    #pragma unroll
    for (int j = 0; j < 4; j++) {
        int o = o0 + wn + j * 16 + mr;
        float gg = g[o], bbv = bb[o];
        float wx = 0.f, wy = 0.f;
        if constexpr (MODE == 1) { wx = w1x[o]; wy = w1y[o]; }
        #pragma unroll
        for (int i = 0; i < 4; i++) {
            #pragma unroll
            for (int r = 0; r < 4; r++) {
                int pix = m0 + wm + i * 16 + q * 4 + r;
                float v = acc[i][j][r];
                if constexpr (MODE == 1) {
                    int n = pix & 4095;
                    float px = E * ((float)(n & 63) * 0.001f + offx);
                    float py = E * ((float)(n >> 6) * 0.001f + offy);
                    v += px * wx + py * wy;
                    v = fmaxf(gg * v + bbv, 0.f);
                } else if constexpr (MODE == 2) {
                    v = fmaxf(gg * v + bbv, 0.f);
                    v = bf2f(res[(size_t)pix * 384 + o]) + rz * v;
                } else if constexpr (MODE == 3) {
                    float t = gg * v + bbv;
                    v = t * fminf(fmaxf(t + 3.f, 0.f), 6.f) * (1.f / 6.f);
                } else {
                    float t = gg * v + bbv;
                    v = bf2f(res[(size_t)pix * 384 + o]) + rz * t;
                }
                out[(size_t)pix * Osz + o] = f2bf(v);
            }
        }
    }
}

// ----------------------------------------------------------- attention ------
// Partial ktv over 4 N-chunks (768 blocks instead of 192 for occupancy);
// attn_apply sums the partials.
__global__ __launch_bounds__(256) void attn_ktv(const u16* __restrict__ proj,
                                                float* __restrict__ ktvp)
{
    int bh = blockIdx.x;
    int ch = blockIdx.y;
    int b = bh / 12, h = bh - b * 12;
    const u16* base = proj + (size_t)b * 4096 * 640;
    int kc = 192 + h * 16, vc = 384 + h * 16;
    __shared__ u16 ks[256 * 16];
    __shared__ u16 vs[256 * 16];
    int t = threadIdx.x;
    int d = t >> 4, e = t & 15;
    float acc = 0.f, ksum = 0.f;
    for (int n0 = ch * 1024; n0 < ch * 1024 + 1024; n0 += 256) {
        __syncthreads();
        const u16* r = base + (size_t)(n0 + t) * 640;
        ((float4*)&ks[t * 16])[0] = ((const float4*)(r + kc))[0];
        ((float4*)&ks[t * 16])[1] = ((const float4*)(r + kc))[1];
        ((float4*)&vs[t * 16])[0] = ((const float4*)(r + vc))[0];
        ((float4*)&vs[t * 16])[1] = ((const float4*)(r + vc))[1];
        __syncthreads();
        #pragma unroll 8
        for (int n = 0; n < 256; n++)
            acc += bf2f(ks[n * 16 + d]) * bf2f(vs[n * 16 + e]);
        if (t < 16) {
            #pragma unroll 8
            for (int n = 0; n < 256; n++) ksum += bf2f(ks[n * 16 + t]);
        }
    }
    float* o = ktvp + ((size_t)bh * 4 + ch) * 272;
    o[t] = acc;
    if (t < 16) o[256 + t] = ksum;
}

__global__ __launch_bounds__(256) void attn_apply(const u16* __restrict__ proj,
                                                  const float* __restrict__ ktvp,
                                                  u16* __restrict__ att)
{
    int bh = blockIdx.x;
    int b = bh / 12, h = bh - b * 12;
    __shared__ float kt[272];
    int t = threadIdx.x;
    {
        const float* p = ktvp + (size_t)bh * 4 * 272;
        kt[t] = p[t] + p[272 + t] + p[544 + t] + p[816 + t];
        if (t < 16) {
            int u = 256 + t;
            kt[u] = p[u] + p[272 + u] + p[544 + u] + p[816 + u];
        }
    }
    __syncthreads();
    int n = blockIdx.y * 256 + t;
    const u16* qr = proj + (size_t)(b * 4096 + n) * 640 + h * 16;
    float qv[16];
    #pragma unroll
    for (int d = 0; d < 16; d++) qv[d] = bf2f(qr[d]);
    float denom = 0.f;
    #pragma unroll
    for (int d = 0; d < 16; d++) denom += qv[d] * kt[256 + d];
    float rcp = 1.f / fmaxf(denom, 1e-4f);
    u16* op = att + (size_t)(b * 4096 + n) * 192 + h * 16;
    #pragma unroll
    for (int e = 0; e < 16; e++) {
        float s = 0.f;
        #pragma unroll
        for (int d = 0; d < 16; d++) s += qv[d] * kt[d * 16 + e];
        op[e] = f2bf(s * rcp);
    }
}

// -------------------------------------------------------- depthwise 5x5 -----
__global__ __launch_bounds__(192) void dwconv(const u16* __restrict__ y,
                                              const float2* __restrict__ wt,
                                              const float* __restrict__ g,
                                              const float* __restrict__ bc,
                                              u16* __restrict__ z)
{
    const int cp = threadIdx.x;        // 0..191
    const int xc = blockIdx.x;         // 0..63
    const int b  = blockIdx.y;         // 0..15
    const int c0 = cp * 2;

    float2 wv[25];
    #pragma unroll
    for (int t = 0; t < 25; t++) wv[t] = wt[t * 192 + cp];
    const float g0 = g[c0], g1 = g[c0 + 1];
    const float b0 = bc[c0], b1 = bc[c0 + 1];

    const size_t ibase = (size_t)b * 4096;
    const u16* ycol = y + ibase * 384 + c0;

    uint32_t r0[5], r1[5], r2[5], r3[5], r4[5];

#define LOADROW(yy, dst)                                                     \
    {                                                                        \
        if ((unsigned)(yy) < 64u) {                                          \
            const u16* rp = ycol + (size_t)(yy) * 64 * 384;                  \
            _Pragma("unroll")                                                \
            for (int dx = 0; dx < 5; dx++) {                                 \
                int xx = xc + dx - 2;                                        \
                dst[dx] = ((unsigned)xx < 64u)                               \
                              ? *(const uint32_t*)(rp + (size_t)xx * 384)    \
                              : 0u;                                          \
            }                                                                \
        } else {                                                             \
            _Pragma("unroll")                                                \
            for (int dx = 0; dx < 5; dx++) dst[dx] = 0u;                     \
        }                                                                    \
    }

#define COMPUTE(yr, A, B, C, D, E)                                           \
    if ((yr) < 64) {                                                         \
        float a0 = 0.f, a1 = 0.f;                                            \
        _Pragma("unroll")                                                    \
        for (int dx = 0; dx < 5; dx++) {                                     \
            uint32_t p;                                                      \
            p = A[dx];                                                       \
            a0 += wv[dx].x * bf2f((u16)(p & 0xffffu));                       \
            a1 += wv[dx].y * bf2f((u16)(p >> 16));                           \
            p = B[dx];                                                       \
            a0 += wv[5 + dx].x * bf2f((u16)(p & 0xffffu));                   \
            a1 += wv[5 + dx].y * bf2f((u16)(p >> 16));                       \
            p = C[dx];                                                       \
            a0 += wv[10 + dx].x * bf2f((u16)(p & 0xffffu));                  \
            a1 += wv[10 + dx].y * bf2f((u16)(p >> 16));                      \
            p = D[dx];                                                       \
            a0 += wv[15 + dx].x * bf2f((u16)(p & 0xffffu));                  \
            a1 += wv[15 + dx].y * bf2f((u16)(p >> 16));                      \
            p = E[dx];                                                       \
            a0 += wv[20 + dx].x * bf2f((u16)(p & 0xffffu));                  \
            a1 += wv[20 + dx].y * bf2f((u16)(p >> 16));                      \
        }                                                                    \
        float t0 = g0 * a0 + b0;                                             \
        float t1 = g1 * a1 + b1;                                             \
        t0 = t0 * fminf(fmaxf(t0 + 3.f, 0.f), 6.f) * (1.f / 6.f);            \
        t1 = t1 * fminf(fmaxf(t1 + 3.f, 0.f), 6.f) * (1.f / 6.f);            \
        uint32_t packed = (uint32_t)f2bf(t0) | ((uint32_t)f2bf(t1) << 16);   \
        *(uint32_t*)(z + (ibase + (size_t)(yr) * 64 + xc) * 384 + c0) = packed; \
    }

#define STEP(yr, A, B, C, D, E)                                              \
    COMPUTE(yr, A, B, C, D, E)                                               \
    LOADROW((yr) + 3, A)

    LOADROW(-2, r0)
    LOADROW(-1, r1)
    LOADROW(0, r2)
    LOADROW(1, r3)
    LOADROW(2, r4)

    for (int base = 0; base < 65; base += 5) {
        STEP(base + 0, r0, r1, r2, r3, r4)
        STEP(base + 1, r1, r2, r3, r4, r0)
        STEP(base + 2, r2, r3, r4, r0, r1)
        STEP(base + 3, r3, r4, r0, r1, r2)
        STEP(base + 4, r4, r0, r1, r2, r3)
    }
#undef STEP
#undef COMPUTE
#undef LOADROW
}

// ---------------------------------------------------------------------------
extern "C" void kernel_launch(void* const* d_in, const int* in_sizes, int n_in,
                              void* d_out, int out_size, void* d_ws, size_t ws_size,
                              hipStream_t stream)
{
    (void)in_sizes; (void)n_in; (void)out_size; (void)ws_size;
    const float* x       = (const float*)d_in[0];
    const float* rnd     = (const float*)d_in[1];
    const float* proj_w  = (const float*)d_in[2];
    const float* proj_g  = (const float*)d_in[3];
    const float* proj_b  = (const float*)d_in[4];
    const float* vp2_w   = (const float*)d_in[5];
    const float* vp2_g   = (const float*)d_in[6];
    const float* vp2_b   = (const float*)d_in[7];
    const float* dw_w    = (const float*)d_in[8];
    const float* dw_g    = (const float*)d_in[9];
    const float* dw_b    = (const float*)d_in[10];
    const float* pw1_w   = (const float*)d_in[11];
    const float* pw1_g   = (const float*)d_in[12];
    const float* pw1_b   = (const float*)d_in[13];
    const float* pw2_w   = (const float*)d_in[14];
    const float* out_g   = (const float*)d_in[15];
    const float* out_b   = (const float*)d_in[16];
    const float* rz_attn = (const float*)d_in[17];
    const float* rz_ffn  = (const float*)d_in[18];
    const float* es      = (const float*)d_in[19];
    float* out = (float*)d_out;

    char* ws = (char*)d_ws;
    u16*   xt   = (u16*)(ws + 0);            // 65536x384 bf16 (z2 aliases from 0)
    u16*   att  = (u16*)(ws + 50331648);     // 65536x192 bf16
    u16*   z2   = (u16*)(ws + 0);            // 65536x1536 bf16 (xt+att dead by then)
    u16*   proj = (u16*)(ws + 201326592);    // 65536x640 bf16
    u16*   z1   = proj;                      // 65536x384 (proj dead)
    u16*   z4   = proj;                      // 65536x384 (z1 dead)
    u16*   yt   = (u16*)(ws + 285212672);    // 65536x384 bf16
    u16*   w1p  = (u16*)(ws + 335753216);    // 640x384 bf16
    u16*   w2   = (u16*)(ws + 336244736);    // 384x192
    u16*   w3   = (u16*)(ws + 336392192);    // 1536x384
    u16*   w4   = (u16*)(ws + 337571840);    // 384x1536
    float* gp   = (float*)(ws + 338751488);  // 4x640 fp32
    float2* dwp = (float2*)(ws + 338761728); // 25x192 float2 (transposed)
    float* ktvp = (float*)(ws + 338800128);  // 192x4x272 fp32 partials

    prep<<<5885, 256, 0, stream>>>(proj_w, proj_g, proj_b, vp2_w, pw1_w, pw2_w,
                                   dw_w, w1p, w2, w3, w4, gp, dwp);
    transpose_x<<<dim3(16, 64, 6), 256, 0, stream>>>(x, xt);
    gemm_nhwc<1><<<2560, 256, 0, stream>>>(xt, w1p, proj, 384, 640, 5,
        gp, gp + 640, gp + 1280, gp + 1920, nullptr, es, rnd);
    attn_ktv<<<dim3(192, 4), 256, 0, stream>>>(proj, ktvp);
    attn_apply<<<dim3(192, 16), 256, 0, stream>>>(proj, ktvp, att);
    gemm_nhwc<2><<<1536, 256, 0, stream>>>(att, w2, yt, 192, 384, 3,
        vp2_g, vp2_b, nullptr, nullptr, xt, rz_attn, nullptr);
    dwconv<<<dim3(64, 16), 192, 0, stream>>>(yt, dwp, dw_g, dw_b, z1);
    gemm_nhwc<3><<<6144, 256, 0, stream>>>(z1, w3, z2, 384, 1536, 12,
        pw1_g, pw1_b, nullptr, nullptr, nullptr, nullptr, nullptr);
    gemm_nhwc<4><<<1536, 256, 0, stream>>>(z2, w4, z4, 1536, 384, 3,
        out_g, out_b, nullptr, nullptr, yt, rz_ffn, nullptr);
    transpose_out<<<dim3(16, 64, 6), 256, 0, stream>>>(z4, out);
}

// Round 3
// 704.177 us; speedup vs baseline: 1.2067x; 1.2067x over previous
//
#include <hip/hip_runtime.h>
#include <cstdint>

typedef unsigned short u16;
typedef __attribute__((ext_vector_type(8))) __bf16 bf16x8;
typedef __attribute__((ext_vector_type(4))) float f32x4;

__device__ __forceinline__ u16 f2bf(float f) {
    union { float f; uint32_t u; } v; v.f = f;
    uint32_t u = v.u;
    uint32_t r = (u + 0x7fffu + ((u >> 16) & 1u)) >> 16;
    return (u16)r;
}
__device__ __forceinline__ float bf2f(u16 h) {
    union { uint32_t u; float f; } v; v.u = ((uint32_t)h) << 16;
    return v.f;
}

// async global->LDS 16B per lane; LDS dest must be wave-uniform base + lane*16
__device__ __forceinline__ void ld_lds16(const u16* g, u16* l) {
    __builtin_amdgcn_global_load_lds(
        (const __attribute__((address_space(1))) uint32_t*)g,
        (__attribute__((address_space(3))) uint32_t*)l, 16, 0, 0);
}

// ---------------------------------------------------------------- prep ------
__global__ __launch_bounds__(256) void prep(
    const float* __restrict__ proj_w, const float* __restrict__ proj_g,
    const float* __restrict__ proj_b, const float* __restrict__ vp2_w,
    const float* __restrict__ pw1_w, const float* __restrict__ pw2_w,
    const float* __restrict__ dw_w,
    u16* __restrict__ w1p, u16* __restrict__ w2, u16* __restrict__ w3,
    u16* __restrict__ w4, float* __restrict__ gp, float2* __restrict__ dwp)
{
    int i = blockIdx.x * 256 + threadIdx.x;
    if (i < 245760) {                 // w1p: 640x384, rows >=576 zero
        int o = i / 384, k = i - o * 384;
        w1p[i] = (o < 576) ? f2bf(proj_w[o * 386 + k]) : (u16)0;
        return;
    }
    i -= 245760;
    if (i < 73728) { w2[i] = f2bf(vp2_w[i]); return; }   // 384x192
    i -= 73728;
    if (i < 589824) { w3[i] = f2bf(pw1_w[i]); return; }  // 1536x384
    i -= 589824;
    if (i < 589824) { w4[i] = f2bf(pw2_w[i]); return; }  // 384x1536
    i -= 589824;
    if (i < 2560) {                   // gp: [g1p|b1p|w1x|w1y] each 640 fp32
        int which = i / 640, o = i - which * 640;
        float v = 0.f;
        if (o < 576) {
            v = (which == 0) ? proj_g[o] : (which == 1) ? proj_b[o]
                : (which == 2) ? proj_w[o * 386 + 384] : proj_w[o * 386 + 385];
        }
        gp[i] = v; return;
    }
    i -= 2560;
    if (i < 4800) {                   // dwp TRANSPOSED: [tap 0..24][cp 0..191]
        int tap = i / 192, cp = i - tap * 192;
        dwp[i] = make_float2(dw_w[(2 * cp) * 25 + tap], dw_w[(2 * cp + 1) * 25 + tap]);
    }
}

// ------------------------------------------------- NCHW fp32 -> NHWC bf16 ---
__global__ __launch_bounds__(256) void transpose_x(const float* __restrict__ x,
                                                   u16* __restrict__ xt)
{
    __shared__ float tile[64][65];
    int b = blockIdx.x, n0 = blockIdx.y * 64, c0 = blockIdx.z * 64;
    int t = threadIdx.x;
    int jj = t & 63, i0 = t >> 6;
    #pragma unroll
    for (int r = 0; r < 16; r++) {
        int ci = r * 4 + i0;
        tile[ci][jj] = x[((size_t)b * 384 + c0 + ci) * 4096 + n0 + jj];
    }
    __syncthreads();
    #pragma unroll
    for (int r = 0; r < 16; r++) {
        int ni = r * 4 + i0;
        xt[(size_t)(b * 4096 + n0 + ni) * 384 + c0 + jj] = f2bf(tile[jj][ni]);
    }
}

// ------------------------------------------------- NHWC bf16 -> NCHW fp32 ---
__global__ __launch_bounds__(256) void transpose_out(const u16* __restrict__ zf,
                                                     float* __restrict__ out)
{
    __shared__ float tile[64][65];
    int b = blockIdx.x, n0 = blockIdx.y * 64, c0 = blockIdx.z * 64;
    int t = threadIdx.x;
    int jj = t & 63, i0 = t >> 6;
    #pragma unroll
    for (int r = 0; r < 16; r++) {
        int ni = r * 4 + i0;
        tile[ni][jj] = bf2f(zf[(size_t)(b * 4096 + n0 + ni) * 384 + c0 + jj]);
    }
    __syncthreads();
    #pragma unroll
    for (int r = 0; r < 16; r++) {
        int ci = r * 4 + i0;
        out[((size_t)b * 384 + c0 + ci) * 4096 + n0 + jj] = tile[jj][ci];
    }
}

// --------------------------------------------------------------- GEMM -------
// Out[pix][o] = epilogue( sum_k A[pix][k] * W[o][k] )   (both k-contiguous)
// v4 = r1 K-loop (3-buffer global_load_lds, counted vmcnt(4), distance-2
// prefetch, XOR bank swizzle, bijective XCD chunking) + s_setprio around the
// MFMA cluster + LDS-bounce coalesced epilogue (vectorized res/g/b loads and
// 16B packed-bf16 stores instead of 16 scalar u16 stores per thread).
template <int MODE>
__global__ __launch_bounds__(256) void gemm_nhwc(
    const u16* __restrict__ A, const u16* __restrict__ W,
    u16* __restrict__ out, int K, int Osz, int nOT,
    const float* __restrict__ g, const float* __restrict__ bb,
    const float* __restrict__ w1x, const float* __restrict__ w1y,
    const u16* __restrict__ res, const float* __restrict__ sc,
    const float* __restrict__ rnd)
{
    constexpr int BK = 32;
    __shared__ u16 sA[3][128 * BK];
    __shared__ u16 sB[3][128 * BK];
    const int tid = threadIdx.x;
    const int lane = tid & 63;
    const int wv = tid >> 6;
    const int wm = (wv >> 1) * 64;
    const int wn = (wv & 1) * 64;

    // bijective XCD chunking: nwg divisible by 8 in all launches
    const int nwg = gridDim.x;
    const int q8 = nwg >> 3;
    const int b1 = (blockIdx.x & 7) * q8 + (blockIdx.x >> 3);
    const int mt = b1 / nOT;
    const int ot = b1 - mt * nOT;
    const int m0 = mt * 128;
    const int o0 = ot * 128;

    const int q = lane >> 4;
    const int mr = lane & 15;
    // swizzled k-slot this lane READS: slot = q ^ ((row>>1)&3); row ≡ mr mod 16
    const int ks = (q ^ ((mr >> 1) & 3)) * 8;

    const int tq = tid >> 2;          // staging row 0..63 (+64 for 2nd group)
    const int sl = tid & 3;           // linear LDS slot (dest is lane-linear)
    const int tk = (sl ^ ((tq >> 1) & 3)) * 8;   // swizzled GLOBAL k-chunk
    const size_t ga0 = (size_t)(m0 + tq) * K + tk;
    const size_t ga1 = (size_t)(m0 + 64 + tq) * K + tk;
    const size_t gb0 = (size_t)(o0 + tq) * K + tk;
    const size_t gb1 = (size_t)(o0 + 64 + tq) * K + tk;
    const int lo0 = tq * BK + sl * 8;
    const int lo1 = (64 + tq) * BK + sl * 8;

    f32x4 acc[4][4] = {};
    const int nIter = K >> 5;

    // prologue: tiles 0 and 1 in flight (4 DMA instrs per wave per tile)
    ld_lds16(A + ga0, &sA[0][lo0]);
    ld_lds16(A + ga1, &sA[0][lo1]);
    ld_lds16(W + gb0, &sB[0][lo0]);
    ld_lds16(W + gb1, &sB[0][lo1]);
    if (nIter > 1) {
        ld_lds16(A + ga0 + BK, &sA[1][lo0]);
        ld_lds16(A + ga1 + BK, &sA[1][lo1]);
        ld_lds16(W + gb0 + BK, &sB[1][lo0]);
        ld_lds16(W + gb1 + BK, &sB[1][lo1]);
    }

    int buf = 0;
    for (int t = 0; t < nIter; ++t) {
        // steady state: 8 own DMAs outstanding (tiles t, t+1); wait-to-4
        // completes tile t. Final iter: only tile t outstanding -> drain.
        if (t + 1 < nIter) asm volatile("s_waitcnt vmcnt(4)" ::: "memory");
        else               asm volatile("s_waitcnt vmcnt(0)" ::: "memory");
        __builtin_amdgcn_s_barrier();
        __builtin_amdgcn_sched_barrier(0);
        if (t + 2 < nIter) {          // prefetch tile t+2 (distance 2)
            int nb = buf + 2; if (nb >= 3) nb -= 3;
            size_t k2 = (size_t)(t + 2) * BK;
            ld_lds16(A + ga0 + k2, &sA[nb][lo0]);
            ld_lds16(A + ga1 + k2, &sA[nb][lo1]);
            ld_lds16(W + gb0 + k2, &sB[nb][lo0]);
            ld_lds16(W + gb1 + k2, &sB[nb][lo1]);
        }
        bf16x8 af[4], bfr[4];
        #pragma unroll
        for (int i = 0; i < 4; i++)
            af[i] = *(const bf16x8*)&sA[buf][(wm + i * 16 + mr) * BK + ks];
        #pragma unroll
        for (int j = 0; j < 4; j++)
            bfr[j] = *(const bf16x8*)&sB[buf][(wn + j * 16 + mr) * BK + ks];
        __builtin_amdgcn_s_setprio(1);
        #pragma unroll
        for (int i = 0; i < 4; i++)
            #pragma unroll
            for (int j = 0; j < 4; j++)
                acc[i][j] = __builtin_amdgcn_mfma_f32_16x16x32_bf16(af[i], bfr[j], acc[i][j], 0, 0, 0);
        __builtin_amdgcn_s_setprio(0);
        buf++; if (buf == 3) buf = 0;
    }

    // -------- coalesced epilogue via LDS bounce (reuses sA, pad 130) --------
    float* st = (float*)&sA[0][0];    // 32 x 130 f32 = 16.6 KB (sA = 24 KB)
    const int wrh = wv >> 1;          // which row-half this wave owns
    const int row_l = tid >> 3;       // read phase: row 0..31
    const int cseg = (tid & 7) * 16;  // read phase: 16-col segment

    float E = 0.f, offx = 0.f, offy = 0.f, rz = 0.f;
    if constexpr (MODE == 1) {
        E = expf(sc[0]);
        int bimg = m0 >> 12;
        offx = rnd[bimg * 2 + 0];
        offy = rnd[bimg * 2 + 1];
    }
    if constexpr (MODE == 2 || MODE == 4) rz = sc[0];

    const int ob = o0 + cseg;
    float gv[16], bv[16];
    #pragma unroll
    for (int c = 0; c < 4; c++) {
        *(float4*)&gv[c * 4] = *(const float4*)(g + ob + c * 4);
        *(float4*)&bv[c * 4] = *(const float4*)(bb + ob + c * 4);
    }
    float wxv[16], wyv[16];
    if constexpr (MODE == 1) {
        #pragma unroll
        for (int c = 0; c < 4; c++) {
            *(float4*)&wxv[c * 4] = *(const float4*)(w1x + ob + c * 4);
            *(float4*)&wyv[c * 4] = *(const float4*)(w1y + ob + c * 4);
        }
    }

    #pragma unroll
    for (int p = 0; p < 4; ++p) {
        __syncthreads();
        if (wrh == (p >> 1)) {        // 2 waves stage their 32-row slab
            const int ib = (p & 1) * 2;
            #pragma unroll
            for (int ii = 0; ii < 2; ++ii)
                #pragma unroll
                for (int j = 0; j < 4; ++j)
                    #pragma unroll
                    for (int r = 0; r < 4; ++r)
                        st[(ii * 16 + q * 4 + r) * 130 + wn + j * 16 + mr] =
                            acc[ib + ii][j][r];
        }
        __syncthreads();
        const int pix = m0 + p * 32 + row_l;
        float vals[16];
        #pragma unroll
        for (int e = 0; e < 16; ++e) vals[e] = st[row_l * 130 + cseg + e];

        u16 rv[16];
        if constexpr (MODE == 2 || MODE == 4) {
            #pragma unroll
            for (int c = 0; c < 2; c++)
                *(float4*)&rv[c * 8] = *(const float4*)(res + (size_t)pix * 384 + ob + c * 8);
        }
        float px = 0.f, py = 0.f;
        if constexpr (MODE == 1) {
            int n = pix & 4095;
            px = E * ((float)(n & 63) * 0.001f + offx);
            py = E * ((float)(n >> 6) * 0.001f + offy);
        }
        u16 ov[16];
        #pragma unroll
        for (int e = 0; e < 16; ++e) {
            float v = vals[e];
            if constexpr (MODE == 1) {
                v += px * wxv[e] + py * wyv[e];
                v = fmaxf(gv[e] * v + bv[e], 0.f);
            } else if constexpr (MODE == 2) {
                v = fmaxf(gv[e] * v + bv[e], 0.f);
                v = bf2f(rv[e]) + rz * v;
            } else if constexpr (MODE == 3) {
                float tv = gv[e] * v + bv[e];
                v = tv * fminf(fmaxf(tv + 3.f, 0.f), 6.f) * (1.f / 6.f);
            } else {
                float tv = gv[e] * v + bv[e];
                v = bf2f(rv[e]) + rz * tv;
            }
            ov[e] = f2bf(v);
        }
        #pragma unroll
        for (int c = 0; c < 2; c++)
            *(float4*)(out + (size_t)pix * Osz + ob + c * 8) = *(const float4*)&ov[c * 8];
    }
}

// ----------------------------------------------------------- attention ------
// Partial ktv over 4 N-chunks (768 blocks instead of 192 for occupancy);
// attn_apply sums the partials.
__global__ __launch_bounds__(256) void attn_ktv(const u16* __restrict__ proj,
                                                float* __restrict__ ktvp)
{
    int bh = blockIdx.x;
    int ch = blockIdx.y;
    int b = bh / 12, h = bh - b * 12;
    const u16* base = proj + (size_t)b * 4096 * 640;
    int kc = 192 + h * 16, vc = 384 + h * 16;
    __shared__ u16 ks[256 * 16];
    __shared__ u16 vs[256 * 16];
    int t = threadIdx.x;
    int d = t >> 4, e = t & 15;
    float acc = 0.f, ksum = 0.f;
    for (int n0 = ch * 1024; n0 < ch * 1024 + 1024; n0 += 256) {
        __syncthreads();
        const u16* r = base + (size_t)(n0 + t) * 640;
        ((float4*)&ks[t * 16])[0] = ((const float4*)(r + kc))[0];
        ((float4*)&ks[t * 16])[1] = ((const float4*)(r + kc))[1];
        ((float4*)&vs[t * 16])[0] = ((const float4*)(r + vc))[0];
        ((float4*)&vs[t * 16])[1] = ((const float4*)(r + vc))[1];
        __syncthreads();
        #pragma unroll 8
        for (int n = 0; n < 256; n++)
            acc += bf2f(ks[n * 16 + d]) * bf2f(vs[n * 16 + e]);
        if (t < 16) {
            #pragma unroll 8
            for (int n = 0; n < 256; n++) ksum += bf2f(ks[n * 16 + t]);
        }
    }
    float* o = ktvp + ((size_t)bh * 4 + ch) * 272;
    o[t] = acc;
    if (t < 16) o[256 + t] = ksum;
}

__global__ __launch_bounds__(256) void attn_apply(const u16* __restrict__ proj,
                                                  const float* __restrict__ ktvp,
                                                  u16* __restrict__ att)
{
    int bh = blockIdx.x;
    int b = bh / 12, h = bh - b * 12;
    __shared__ float kt[272];
    int t = threadIdx.x;
    {
        const float* p = ktvp + (size_t)bh * 4 * 272;
        kt[t] = p[t] + p[272 + t] + p[544 + t] + p[816 + t];
        if (t < 16) {
            int u = 256 + t;
            kt[u] = p[u] + p[272 + u] + p[544 + u] + p[816 + u];
        }
    }
    __syncthreads();
    int n = blockIdx.y * 256 + t;
    const u16* qr = proj + (size_t)(b * 4096 + n) * 640 + h * 16;
    float qv[16];
    #pragma unroll
    for (int d = 0; d < 16; d++) qv[d] = bf2f(qr[d]);
    float denom = 0.f;
    #pragma unroll
    for (int d = 0; d < 16; d++) denom += qv[d] * kt[256 + d];
    float rcp = 1.f / fmaxf(denom, 1e-4f);
    u16* op = att + (size_t)(b * 4096 + n) * 192 + h * 16;
    #pragma unroll
    for (int e = 0; e < 16; e++) {
        float s = 0.f;
        #pragma unroll
        for (int d = 0; d < 16; d++) s += qv[d] * kt[d * 16 + e];
        op[e] = f2bf(s * rcp);
    }
}

// -------------------------------------------------------- depthwise 5x5 -----
__global__ __launch_bounds__(192) void dwconv(const u16* __restrict__ y,
                                              const float2* __restrict__ wt,
                                              const float* __restrict__ g,
                                              const float* __restrict__ bc,
                                              u16* __restrict__ z)
{
    const int cp = threadIdx.x;        // 0..191
    const int xc = blockIdx.x;         // 0..63
    const int b  = blockIdx.y;         // 0..15
    const int c0 = cp * 2;

    float2 wv[25];
    #pragma unroll
    for (int t = 0; t < 25; t++) wv[t] = wt[t * 192 + cp];
    const float g0 = g[c0], g1 = g[c0 + 1];
    const float b0 = bc[c0], b1 = bc[c0 + 1];

    const size_t ibase = (size_t)b * 4096;
    const u16* ycol = y + ibase * 384 + c0;

    uint32_t r0[5], r1[5], r2[5], r3[5], r4[5];

#define LOADROW(yy, dst)                                                     \
    {                                                                        \
        if ((unsigned)(yy) < 64u) {                                          \
            const u16* rp = ycol + (size_t)(yy) * 64 * 384;                  \
            _Pragma("unroll")                                                \
            for (int dx = 0; dx < 5; dx++) {                                 \
                int xx = xc + dx - 2;                                        \
                dst[dx] = ((unsigned)xx < 64u)                               \
                              ? *(const uint32_t*)(rp + (size_t)xx * 384)    \
                              : 0u;                                          \
            }                                                                \
        } else {                                                             \
            _Pragma("unroll")                                                \
            for (int dx = 0; dx < 5; dx++) dst[dx] = 0u;                     \
        }                                                                    \
    }

#define COMPUTE(yr, A, B, C, D, E)                                           \
    if ((yr) < 64) {                                                         \
        float a0 = 0.f, a1 = 0.f;                                            \
        _Pragma("unroll")                                                    \
        for (int dx = 0; dx < 5; dx++) {                                     \
            uint32_t p;                                                      \
            p = A[dx];                                                       \
            a0 += wv[dx].x * bf2f((u16)(p & 0xffffu));                       \
            a1 += wv[dx].y * bf2f((u16)(p >> 16));                           \
            p = B[dx];                                                       \
            a0 += wv[5 + dx].x * bf2f((u16)(p & 0xffffu));                   \
            a1 += wv[5 + dx].y * bf2f((u16)(p >> 16));                       \
            p = C[dx];                                                       \
            a0 += wv[10 + dx].x * bf2f((u16)(p & 0xffffu));                  \
            a1 += wv[10 + dx].y * bf2f((u16)(p >> 16));                      \
            p = D[dx];                                                       \
            a0 += wv[15 + dx].x * bf2f((u16)(p & 0xffffu));                  \
            a1 += wv[15 + dx].y * bf2f((u16)(p >> 16));                      \
            p = E[dx];                                                       \
            a0 += wv[20 + dx].x * bf2f((u16)(p & 0xffffu));                  \
            a1 += wv[20 + dx].y * bf2f((u16)(p >> 16));                      \
        }                                                                    \
        float t0 = g0 * a0 + b0;                                             \
        float t1 = g1 * a1 + b1;                                             \
        t0 = t0 * fminf(fmaxf(t0 + 3.f, 0.f), 6.f) * (1.f / 6.f);            \
        t1 = t1 * fminf(fmaxf(t1 + 3.f, 0.f), 6.f) * (1.f / 6.f);            \
        uint32_t packed = (uint32_t)f2bf(t0) | ((uint32_t)f2bf(t1) << 16);   \
        *(uint32_t*)(z + (ibase + (size_t)(yr) * 64 + xc) * 384 + c0) = packed; \
    }

#define STEP(yr, A, B, C, D, E)                                              \
    COMPUTE(yr, A, B, C, D, E)                                               \
    LOADROW((yr) + 3, A)

    LOADROW(-2, r0)
    LOADROW(-1, r1)
    LOADROW(0, r2)
    LOADROW(1, r3)
    LOADROW(2, r4)

    for (int base = 0; base < 65; base += 5) {
        STEP(base + 0, r0, r1, r2, r3, r4)
        STEP(base + 1, r1, r2, r3, r4, r0)
        STEP(base + 2, r2, r3, r4, r0, r1)
        STEP(base + 3, r3, r4, r0, r1, r2)
        STEP(base + 4, r4, r0, r1, r2, r3)
    }
#undef STEP
#undef COMPUTE
#undef LOADROW
}

// ---------------------------------------------------------------------------
extern "C" void kernel_launch(void* const* d_in, const int* in_sizes, int n_in,
                              void* d_out, int out_size, void* d_ws, size_t ws_size,
                              hipStream_t stream)
{
    (void)in_sizes; (void)n_in; (void)out_size; (void)ws_size;
    const float* x       = (const float*)d_in[0];
    const float* rnd     = (const float*)d_in[1];
    const float* proj_w  = (const float*)d_in[2];
    const float* proj_g  = (const float*)d_in[3];
    const float* proj_b  = (const float*)d_in[4];
    const float* vp2_w   = (const float*)d_in[5];
    const float* vp2_g   = (const float*)d_in[6];
    const float* vp2_b   = (const float*)d_in[7];
    const float* dw_w    = (const float*)d_in[8];
    const float* dw_g    = (const float*)d_in[9];
    const float* dw_b    = (const float*)d_in[10];
    const float* pw1_w   = (const float*)d_in[11];
    const float* pw1_g   = (const float*)d_in[12];
    const float* pw1_b   = (const float*)d_in[13];
    const float* pw2_w   = (const float*)d_in[14];
    const float* out_g   = (const float*)d_in[15];
    const float* out_b   = (const float*)d_in[16];
    const float* rz_attn = (const float*)d_in[17];
    const float* rz_ffn  = (const float*)d_in[18];
    const float* es      = (const float*)d_in[19];
    float* out = (float*)d_out;

    char* ws = (char*)d_ws;
    u16*   xt   = (u16*)(ws + 0);            // 65536x384 bf16 (z2 aliases from 0)
    u16*   att  = (u16*)(ws + 50331648);     // 65536x192 bf16
    u16*   z2   = (u16*)(ws + 0);            // 65536x1536 bf16 (xt+att dead by then)
    u16*   proj = (u16*)(ws + 201326592);    // 65536x640 bf16
    u16*   z1   = proj;                      // 65536x384 (proj dead)
    u16*   z4   = proj;                      // 65536x384 (z1 dead)
    u16*   yt   = (u16*)(ws + 285212672);    // 65536x384 bf16
    u16*   w1p  = (u16*)(ws + 335753216);    // 640x384 bf16
    u16*   w2   = (u16*)(ws + 336244736);    // 384x192
    u16*   w3   = (u16*)(ws + 336392192);    // 1536x384
    u16*   w4   = (u16*)(ws + 337571840);    // 384x1536
    float* gp   = (float*)(ws + 338751488);  // 4x640 fp32
    float2* dwp = (float2*)(ws + 338761728); // 25x192 float2 (transposed)
    float* ktvp = (float*)(ws + 338800128);  // 192x4x272 fp32 partials

    prep<<<5885, 256, 0, stream>>>(proj_w, proj_g, proj_b, vp2_w, pw1_w, pw2_w,
                                   dw_w, w1p, w2, w3, w4, gp, dwp);
    transpose_x<<<dim3(16, 64, 6), 256, 0, stream>>>(x, xt);
    gemm_nhwc<1><<<2560, 256, 0, stream>>>(xt, w1p, proj, 384, 640, 5,
        gp, gp + 640, gp + 1280, gp + 1920, nullptr, es, rnd);
    attn_ktv<<<dim3(192, 4), 256, 0, stream>>>(proj, ktvp);
    attn_apply<<<dim3(192, 16), 256, 0, stream>>>(proj, ktvp, att);
    gemm_nhwc<2><<<1536, 256, 0, stream>>>(att, w2, yt, 192, 384, 3,
        vp2_g, vp2_b, nullptr, nullptr, xt, rz_attn, nullptr);
    dwconv<<<dim3(64, 16), 192, 0, stream>>>(yt, dwp, dw_g, dw_b, z1);
    gemm_nhwc<3><<<6144, 256, 0, stream>>>(z1, w3, z2, 384, 1536, 12,
        pw1_g, pw1_b, nullptr, nullptr, nullptr, nullptr, nullptr);
    gemm_nhwc<4><<<1536, 256, 0, stream>>>(z2, w4, z4, 1536, 384, 3,
        out_g, out_b, nullptr, nullptr, yt, rz_ffn, nullptr);
    transpose_out<<<dim3(16, 64, 6), 256, 0, stream>>>(z4, out);
}

// Round 4
// 699.819 us; speedup vs baseline: 1.2142x; 1.0062x over previous
//
#include <hip/hip_runtime.h>
#include <cstdint>

typedef unsigned short u16;
typedef __attribute__((ext_vector_type(8))) __bf16 bf16x8;
typedef __attribute__((ext_vector_type(4))) float f32x4;

__device__ __forceinline__ u16 f2bf(float f) {
    union { float f; uint32_t u; } v; v.f = f;
    uint32_t u = v.u;
    uint32_t r = (u + 0x7fffu + ((u >> 16) & 1u)) >> 16;
    return (u16)r;
}
__device__ __forceinline__ float bf2f(u16 h) {
    union { uint32_t u; float f; } v; v.u = ((uint32_t)h) << 16;
    return v.f;
}

// async global->LDS 16B per lane; LDS dest must be wave-uniform base + lane*16
__device__ __forceinline__ void ld_lds16(const u16* g, u16* l) {
    __builtin_amdgcn_global_load_lds(
        (const __attribute__((address_space(1))) uint32_t*)g,
        (__attribute__((address_space(3))) uint32_t*)l, 16, 0, 0);
}

// ---------------------------------------------------------------- prep ------
__global__ __launch_bounds__(256) void prep(
    const float* __restrict__ proj_w, const float* __restrict__ proj_g,
    const float* __restrict__ proj_b, const float* __restrict__ vp2_w,
    const float* __restrict__ pw1_w, const float* __restrict__ pw2_w,
    const float* __restrict__ dw_w,
    u16* __restrict__ w1p, u16* __restrict__ w2, u16* __restrict__ w3,
    u16* __restrict__ w4, float* __restrict__ gp, float2* __restrict__ dwp)
{
    int i = blockIdx.x * 256 + threadIdx.x;
    if (i < 245760) {                 // w1p: 640x384, rows >=576 zero
        int o = i / 384, k = i - o * 384;
        w1p[i] = (o < 576) ? f2bf(proj_w[o * 386 + k]) : (u16)0;
        return;
    }
    i -= 245760;
    if (i < 73728) { w2[i] = f2bf(vp2_w[i]); return; }   // 384x192
    i -= 73728;
    if (i < 589824) { w3[i] = f2bf(pw1_w[i]); return; }  // 1536x384
    i -= 589824;
    if (i < 589824) { w4[i] = f2bf(pw2_w[i]); return; }  // 384x1536
    i -= 589824;
    if (i < 2560) {                   // gp: [g1p|b1p|w1x|w1y] each 640 fp32
        int which = i / 640, o = i - which * 640;
        float v = 0.f;
        if (o < 576) {
            v = (which == 0) ? proj_g[o] : (which == 1) ? proj_b[o]
                : (which == 2) ? proj_w[o * 386 + 384] : proj_w[o * 386 + 385];
        }
        gp[i] = v; return;
    }
    i -= 2560;
    if (i < 4800) {                   // dwp TRANSPOSED: [tap 0..24][cp 0..191]
        int tap = i / 192, cp = i - tap * 192;
        dwp[i] = make_float2(dw_w[(2 * cp) * 25 + tap], dw_w[(2 * cp + 1) * 25 + tap]);
    }
}

// ------------------------------------------------- NCHW fp32 -> NHWC bf16 ---
__global__ __launch_bounds__(256) void transpose_x(const float* __restrict__ x,
                                                   u16* __restrict__ xt)
{
    __shared__ float tile[64][65];
    int b = blockIdx.x, n0 = blockIdx.y * 64, c0 = blockIdx.z * 64;
    int t = threadIdx.x;
    int jj = t & 63, i0 = t >> 6;
    #pragma unroll
    for (int r = 0; r < 16; r++) {
        int ci = r * 4 + i0;
        tile[ci][jj] = x[((size_t)b * 384 + c0 + ci) * 4096 + n0 + jj];
    }
    __syncthreads();
    #pragma unroll
    for (int r = 0; r < 16; r++) {
        int ni = r * 4 + i0;
        xt[(size_t)(b * 4096 + n0 + ni) * 384 + c0 + jj] = f2bf(tile[jj][ni]);
    }
}

// ------------------------------------------------- NHWC bf16 -> NCHW fp32 ---
__global__ __launch_bounds__(256) void transpose_out(const u16* __restrict__ zf,
                                                     float* __restrict__ out)
{
    __shared__ float tile[64][65];
    int b = blockIdx.x, n0 = blockIdx.y * 64, c0 = blockIdx.z * 64;
    int t = threadIdx.x;
    int jj = t & 63, i0 = t >> 6;
    #pragma unroll
    for (int r = 0; r < 16; r++) {
        int ni = r * 4 + i0;
        tile[ni][jj] = bf2f(zf[(size_t)(b * 4096 + n0 + ni) * 384 + c0 + jj]);
    }
    __syncthreads();
    #pragma unroll
    for (int r = 0; r < 16; r++) {
        int ci = r * 4 + i0;
        out[((size_t)b * 384 + c0 + ci) * 4096 + n0 + jj] = tile[jj][ci];
    }
}

// --------------------------------------------------------------- GEMM -------
// Out[pix][o] = epilogue( sum_k A[pix][k] * W[o][k] )   (both k-contiguous)
// v5: templated tile geometry. Block = 2x2 waves, wave-tile (IM*16)x(JN*16).
//   cfg A (IM=4,JN=4): 128x128, NBUF=3, counted vmcnt(4), distance-2.
//   fat  (IM+JN=12) : 128x256 / 256x128, NBUF=2, 48 KB LDS, distance-1 —
//     12 LDS frags feed 32 MFMA (43.7 FLOP/B) so the LDS-read pipe no longer
//     binds, and iterations are long enough to cover HBM latency.
// XOR bank swizzle (source-side + read-side), bijective XCD chunking,
// s_setprio around MFMA, coalesced LDS-bounce epilogue.
template <int MODE, int IM, int JN>
__global__ __launch_bounds__(256) void gemm_nhwc(
    const u16* __restrict__ A, const u16* __restrict__ W,
    u16* __restrict__ out, int K, int Osz, int nOT,
    const float* __restrict__ g, const float* __restrict__ bb,
    const float* __restrict__ w1x, const float* __restrict__ w1y,
    const u16* __restrict__ res, const float* __restrict__ sc,
    const float* __restrict__ rnd)
{
    constexpr int BK = 32;
    constexpr int BM = IM * 32;
    constexpr int BN = JN * 32;
    constexpr int GA = IM / 2;        // 64-row staging groups for A
    constexpr int GB = JN / 2;
    constexpr int NCH = GA + GB;      // DMA instrs per thread per tile
    constexpr int NBUF = ((BM + BN) * 64 * 3 <= 49152) ? 3 : 2;
    __shared__ u16 smem[NBUF * (BM + BN) * BK];   // 48 KB in all configs

    const int tid = threadIdx.x;
    const int lane = tid & 63;
    const int wv = tid >> 6;
    const int wm = (wv >> 1) * (IM * 16);
    const int wn = (wv & 1) * (JN * 16);

    // bijective XCD chunking: nwg divisible by 8 in all launches
    const int nwg = gridDim.x;
    const int q8 = nwg >> 3;
    const int b1 = (blockIdx.x & 7) * q8 + (blockIdx.x >> 3);
    const int mt = b1 / nOT;
    const int ot = b1 - mt * nOT;
    const int m0 = mt * BM;
    const int o0 = ot * BN;

    const int q = lane >> 4;
    const int mr = lane & 15;
    // swizzled k-slot this lane READS: slot = q ^ ((row>>1)&3); row ≡ mr mod 16
    const int ks = (q ^ ((mr >> 1) & 3)) * 8;

    const int tq = tid >> 2;          // staging row 0..63 within group
    const int sl = tid & 3;           // linear LDS slot (dest is lane-linear)
    const int tk = (sl ^ ((tq >> 1) & 3)) * 8;   // swizzled GLOBAL k-chunk

    size_t ga[GA], gb[GB];
    int la[GA], lb[GB];
    #pragma unroll
    for (int gi = 0; gi < GA; gi++) {
        ga[gi] = (size_t)(m0 + gi * 64 + tq) * K + tk;
        la[gi] = (gi * 64 + tq) * BK + sl * 8;
    }
    #pragma unroll
    for (int gi = 0; gi < GB; gi++) {
        gb[gi] = (size_t)(o0 + gi * 64 + tq) * K + tk;
        lb[gi] = (gi * 64 + tq) * BK + sl * 8;
    }

#define STAGE(TILE, BUFI)                                                    \
    {                                                                        \
        const size_t ko = (size_t)(TILE) * BK;                               \
        u16* sAb = smem + (BUFI) * (BM * BK);                                \
        u16* sBb = smem + NBUF * (BM * BK) + (BUFI) * (BN * BK);             \
        _Pragma("unroll")                                                    \
        for (int gi = 0; gi < GA; gi++)                                      \
            ld_lds16(A + ga[gi] + ko, sAb + la[gi]);                         \
        _Pragma("unroll")                                                    \
        for (int gi = 0; gi < GB; gi++)                                      \
            ld_lds16(W + gb[gi] + ko, sBb + lb[gi]);                         \
    }

    f32x4 acc[IM][JN] = {};
    const int nIter = K >> 5;

    STAGE(0, 0)
    if (NBUF == 3 && nIter > 1) STAGE(1, 1)

    int buf = 0;
    for (int t = 0; t < nIter; ++t) {
        if constexpr (NBUF == 3) {
            // steady: tiles t,t+1 in flight (2*NCH); wait-to-NCH completes t
            if (t + 1 < nIter)
                asm volatile("s_waitcnt vmcnt(%0)" ::"i"(NCH) : "memory");
            else
                asm volatile("s_waitcnt vmcnt(0)" ::: "memory");
        } else {
            asm volatile("s_waitcnt vmcnt(0)" ::: "memory");
        }
        __builtin_amdgcn_s_barrier();
        __builtin_amdgcn_sched_barrier(0);
        if (t + NBUF - 1 < nIter) {   // prefetch into next free buffer
            int nb = buf + (NBUF - 1); if (nb >= NBUF) nb -= NBUF;
            STAGE(t + NBUF - 1, nb)
        }
        const u16* sAr = smem + buf * (BM * BK);
        const u16* sBr = smem + NBUF * (BM * BK) + buf * (BN * BK);
        bf16x8 af[IM], bfr[JN];
        #pragma unroll
        for (int i = 0; i < IM; i++)
            af[i] = *(const bf16x8*)&sAr[(wm + i * 16 + mr) * BK + ks];
        #pragma unroll
        for (int j = 0; j < JN; j++)
            bfr[j] = *(const bf16x8*)&sBr[(wn + j * 16 + mr) * BK + ks];
        __builtin_amdgcn_s_setprio(1);
        #pragma unroll
        for (int i = 0; i < IM; i++)
            #pragma unroll
            for (int j = 0; j < JN; j++)
                acc[i][j] = __builtin_amdgcn_mfma_f32_16x16x32_bf16(af[i], bfr[j], acc[i][j], 0, 0, 0);
        __builtin_amdgcn_s_setprio(0);
        buf++; if (buf == NBUF) buf = 0;
    }
#undef STAGE

    // -------- coalesced epilogue via LDS bounce (reuses smem) --------------
    float* st = (float*)smem;         // 32 x (BN+2) f32
    constexpr int P = BM / 32;        // 32-row phases
    constexpr int HP = IM / 2;        // phases per wave-row-half
    constexpr int NG = BN / 128;      // 128-col groups
    const int row_l = tid >> 3;       // read phase: row 0..31
    const int cs16 = (tid & 7) * 16;  // read phase: 16-col segment

    float E = 0.f, offx = 0.f, offy = 0.f, rz = 0.f;
    if constexpr (MODE == 1) {
        E = expf(sc[0]);
        int bimg = m0 >> 12;
        offx = rnd[bimg * 2 + 0];
        offy = rnd[bimg * 2 + 1];
    }
    if constexpr (MODE == 2 || MODE == 4) rz = sc[0];

    float gv[NG][16], bv[NG][16];
    #pragma unroll
    for (int gg = 0; gg < NG; gg++)
        #pragma unroll
        for (int c = 0; c < 4; c++) {
            *(float4*)&gv[gg][c * 4] = *(const float4*)(g + o0 + gg * 128 + cs16 + c * 4);
            *(float4*)&bv[gg][c * 4] = *(const float4*)(bb + o0 + gg * 128 + cs16 + c * 4);
        }
    float wxv[16], wyv[16];
    if constexpr (MODE == 1) {        // MODE1 always uses NG==1 geometry
        #pragma unroll
        for (int c = 0; c < 4; c++) {
            *(float4*)&wxv[c * 4] = *(const float4*)(w1x + o0 + cs16 + c * 4);
            *(float4*)&wyv[c * 4] = *(const float4*)(w1y + o0 + cs16 + c * 4);
        }
    }

    #pragma unroll
    for (int p = 0; p < P; ++p) {
        __syncthreads();
        if ((wv >> 1) == p / HP) {    // 2 waves stage this 32-row slab
            const int ib = (p % HP) * 2;
            #pragma unroll
            for (int ii = 0; ii < 2; ++ii)
                #pragma unroll
                for (int j = 0; j < JN; ++j)
                    #pragma unroll
                    for (int r = 0; r < 4; ++r)
                        st[(ii * 16 + q * 4 + r) * (BN + 2) + wn + j * 16 + mr] =
                            acc[ib + ii][j][r];
        }
        __syncthreads();
        const int pix = m0 + p * 32 + row_l;
        float px = 0.f, py = 0.f;
        if constexpr (MODE == 1) {
            int n = pix & 4095;
            px = E * ((float)(n & 63) * 0.001f + offx);
            py = E * ((float)(n >> 6) * 0.001f + offy);
        }
        #pragma unroll
        for (int gg = 0; gg < NG; ++gg) {
            const int ob = o0 + gg * 128 + cs16;
            float vals[16];
            #pragma unroll
            for (int e = 0; e < 16; ++e)
                vals[e] = st[row_l * (BN + 2) + gg * 128 + cs16 + e];
            u16 rv[16];
            if constexpr (MODE == 2 || MODE == 4) {
                #pragma unroll
                for (int c = 0; c < 2; c++)
                    *(float4*)&rv[c * 8] = *(const float4*)(res + (size_t)pix * 384 + ob + c * 8);
            }
            u16 ov[16];
            #pragma unroll
            for (int e = 0; e < 16; ++e) {
                float v = vals[e];
                if constexpr (MODE == 1) {
                    v += px * wxv[e] + py * wyv[e];
                    v = fmaxf(gv[gg][e] * v + bv[gg][e], 0.f);
                } else if constexpr (MODE == 2) {
                    v = fmaxf(gv[gg][e] * v + bv[gg][e], 0.f);
                    v = bf2f(rv[e]) + rz * v;
                } else if constexpr (MODE == 3) {
                    float tv = gv[gg][e] * v + bv[gg][e];
                    v = tv * fminf(fmaxf(tv + 3.f, 0.f), 6.f) * (1.f / 6.f);
                } else {
                    float tv = gv[gg][e] * v + bv[gg][e];
                    v = bf2f(rv[e]) + rz * tv;
                }
                ov[e] = f2bf(v);
            }
            #pragma unroll
            for (int c = 0; c < 2; c++)
                *(float4*)(out + (size_t)pix * Osz + ob + c * 8) = *(const float4*)&ov[c * 8];
        }
    }
}

// ----------------------------------------------------------- attention ------
// Partial ktv over 4 N-chunks (768 blocks instead of 192 for occupancy);
// attn_apply sums the partials.
__global__ __launch_bounds__(256) void attn_ktv(const u16* __restrict__ proj,
                                                float* __restrict__ ktvp)
{
    int bh = blockIdx.x;
    int ch = blockIdx.y;
    int b = bh / 12, h = bh - b * 12;
    const u16* base = proj + (size_t)b * 4096 * 640;
    int kc = 192 + h * 16, vc = 384 + h * 16;
    __shared__ u16 ks[256 * 16];
    __shared__ u16 vs[256 * 16];
    int t = threadIdx.x;
    int d = t >> 4, e = t & 15;
    float acc = 0.f, ksum = 0.f;
    for (int n0 = ch * 1024; n0 < ch * 1024 + 1024; n0 += 256) {
        __syncthreads();
        const u16* r = base + (size_t)(n0 + t) * 640;
        ((float4*)&ks[t * 16])[0] = ((const float4*)(r + kc))[0];
        ((float4*)&ks[t * 16])[1] = ((const float4*)(r + kc))[1];
        ((float4*)&vs[t * 16])[0] = ((const float4*)(r + vc))[0];
        ((float4*)&vs[t * 16])[1] = ((const float4*)(r + vc))[1];
        __syncthreads();
        #pragma unroll 8
        for (int n = 0; n < 256; n++)
            acc += bf2f(ks[n * 16 + d]) * bf2f(vs[n * 16 + e]);
        if (t < 16) {
            #pragma unroll 8
            for (int n = 0; n < 256; n++) ksum += bf2f(ks[n * 16 + t]);
        }
    }
    float* o = ktvp + ((size_t)bh * 4 + ch) * 272;
    o[t] = acc;
    if (t < 16) o[256 + t] = ksum;
}

__global__ __launch_bounds__(256) void attn_apply(const u16* __restrict__ proj,
                                                  const float* __restrict__ ktvp,
                                                  u16* __restrict__ att)
{
    int bh = blockIdx.x;
    int b = bh / 12, h = bh - b * 12;
    __shared__ float kt[272];
    int t = threadIdx.x;
    {
        const float* p = ktvp + (size_t)bh * 4 * 272;
        kt[t] = p[t] + p[272 + t] + p[544 + t] + p[816 + t];
        if (t < 16) {
            int u = 256 + t;
            kt[u] = p[u] + p[272 + u] + p[544 + u] + p[816 + u];
        }
    }
    __syncthreads();
    int n = blockIdx.y * 256 + t;
    const u16* qr = proj + (size_t)(b * 4096 + n) * 640 + h * 16;
    float qv[16];
    #pragma unroll
    for (int d = 0; d < 16; d++) qv[d] = bf2f(qr[d]);
    float denom = 0.f;
    #pragma unroll
    for (int d = 0; d < 16; d++) denom += qv[d] * kt[256 + d];
    float rcp = 1.f / fmaxf(denom, 1e-4f);
    u16* op = att + (size_t)(b * 4096 + n) * 192 + h * 16;
    #pragma unroll
    for (int e = 0; e < 16; e++) {
        float s = 0.f;
        #pragma unroll
        for (int d = 0; d < 16; d++) s += qv[d] * kt[d * 16 + e];
        op[e] = f2bf(s * rcp);
    }
}

// -------------------------------------------------------- depthwise 5x5 -----
__global__ __launch_bounds__(192) void dwconv(const u16* __restrict__ y,
                                              const float2* __restrict__ wt,
                                              const float* __restrict__ g,
                                              const float* __restrict__ bc,
                                              u16* __restrict__ z)
{
    const int cp = threadIdx.x;        // 0..191
    const int xc = blockIdx.x;         // 0..63
    const int b  = blockIdx.y;         // 0..15
    const int c0 = cp * 2;

    float2 wv[25];
    #pragma unroll
    for (int t = 0; t < 25; t++) wv[t] = wt[t * 192 + cp];
    const float g0 = g[c0], g1 = g[c0 + 1];
    const float b0 = bc[c0], b1 = bc[c0 + 1];

    const size_t ibase = (size_t)b * 4096;
    const u16* ycol = y + ibase * 384 + c0;

    uint32_t r0[5], r1[5], r2[5], r3[5], r4[5];

#define LOADROW(yy, dst)                                                     \
    {                                                                        \
        if ((unsigned)(yy) < 64u) {                                          \
            const u16* rp = ycol + (size_t)(yy) * 64 * 384;                  \
            _Pragma("unroll")                                                \
            for (int dx = 0; dx < 5; dx++) {                                 \
                int xx = xc + dx - 2;                                        \
                dst[dx] = ((unsigned)xx < 64u)                               \
                              ? *(const uint32_t*)(rp + (size_t)xx * 384)    \
                              : 0u;                                          \
            }                                                                \
        } else {                                                             \
            _Pragma("unroll")                                                \
            for (int dx = 0; dx < 5; dx++) dst[dx] = 0u;                     \
        }                                                                    \
    }

#define COMPUTE(yr, A, B, C, D, E)                                           \
    if ((yr) < 64) {                                                         \
        float a0 = 0.f, a1 = 0.f;                                            \
        _Pragma("unroll")                                                    \
        for (int dx = 0; dx < 5; dx++) {                                     \
            uint32_t p;                                                      \
            p = A[dx];                                                       \
            a0 += wv[dx].x * bf2f((u16)(p & 0xffffu));                       \
            a1 += wv[dx].y * bf2f((u16)(p >> 16));                           \
            p = B[dx];                                                       \
            a0 += wv[5 + dx].x * bf2f((u16)(p & 0xffffu));                   \
            a1 += wv[5 + dx].y * bf2f((u16)(p >> 16));                       \
            p = C[dx];                                                       \
            a0 += wv[10 + dx].x * bf2f((u16)(p & 0xffffu));                  \
            a1 += wv[10 + dx].y * bf2f((u16)(p >> 16));                      \
            p = D[dx];                                                       \
            a0 += wv[15 + dx].x * bf2f((u16)(p & 0xffffu));                  \
            a1 += wv[15 + dx].y * bf2f((u16)(p >> 16));                      \
            p = E[dx];                                                       \
            a0 += wv[20 + dx].x * bf2f((u16)(p & 0xffffu));                  \
            a1 += wv[20 + dx].y * bf2f((u16)(p >> 16));                      \
        }                                                                    \
        float t0 = g0 * a0 + b0;                                             \
        float t1 = g1 * a1 + b1;                                             \
        t0 = t0 * fminf(fmaxf(t0 + 3.f, 0.f), 6.f) * (1.f / 6.f);            \
        t1 = t1 * fminf(fmaxf(t1 + 3.f, 0.f), 6.f) * (1.f / 6.f);            \
        uint32_t packed = (uint32_t)f2bf(t0) | ((uint32_t)f2bf(t1) << 16);   \
        *(uint32_t*)(z + (ibase + (size_t)(yr) * 64 + xc) * 384 + c0) = packed; \
    }

#define STEP(yr, A, B, C, D, E)                                              \
    COMPUTE(yr, A, B, C, D, E)                                               \
    LOADROW((yr) + 3, A)

    LOADROW(-2, r0)
    LOADROW(-1, r1)
    LOADROW(0, r2)
    LOADROW(1, r3)
    LOADROW(2, r4)

    for (int base = 0; base < 65; base += 5) {
        STEP(base + 0, r0, r1, r2, r3, r4)
        STEP(base + 1, r1, r2, r3, r4, r0)
        STEP(base + 2, r2, r3, r4, r0, r1)
        STEP(base + 3, r3, r4, r0, r1, r2)
        STEP(base + 4, r4, r0, r1, r2, r3)
    }
#undef STEP
#undef COMPUTE
#undef LOADROW
}

// ---------------------------------------------------------------------------
extern "C" void kernel_launch(void* const* d_in, const int* in_sizes, int n_in,
                              void* d_out, int out_size, void* d_ws, size_t ws_size,
                              hipStream_t stream)
{
    (void)in_sizes; (void)n_in; (void)out_size; (void)ws_size;
    const float* x       = (const float*)d_in[0];
    const float* rnd     = (const float*)d_in[1];
    const float* proj_w  = (const float*)d_in[2];
    const float* proj_g  = (const float*)d_in[3];
    const float* proj_b  = (const float*)d_in[4];
    const float* vp2_w   = (const float*)d_in[5];
    const float* vp2_g   = (const float*)d_in[6];
    const float* vp2_b   = (const float*)d_in[7];
    const float* dw_w    = (const float*)d_in[8];
    const float* dw_g    = (const float*)d_in[9];
    const float* dw_b    = (const float*)d_in[10];
    const float* pw1_w   = (const float*)d_in[11];
    const float* pw1_g   = (const float*)d_in[12];
    const float* pw1_b   = (const float*)d_in[13];
    const float* pw2_w   = (const float*)d_in[14];
    const float* out_g   = (const float*)d_in[15];
    const float* out_b   = (const float*)d_in[16];
    const float* rz_attn = (const float*)d_in[17];
    const float* rz_ffn  = (const float*)d_in[18];
    const float* es      = (const float*)d_in[19];
    float* out = (float*)d_out;

    char* ws = (char*)d_ws;
    u16*   xt   = (u16*)(ws + 0);            // 65536x384 bf16 (z2 aliases from 0)
    u16*   att  = (u16*)(ws + 50331648);     // 65536x192 bf16
    u16*   z2   = (u16*)(ws + 0);            // 65536x1536 bf16 (xt+att dead by then)
    u16*   proj = (u16*)(ws + 201326592);    // 65536x640 bf16
    u16*   z1   = proj;                      // 65536x384 (proj dead)
    u16*   z4   = proj;                      // 65536x384 (z1 dead)
    u16*   yt   = (u16*)(ws + 285212672);    // 65536x384 bf16
    u16*   w1p  = (u16*)(ws + 335753216);    // 640x384 bf16
    u16*   w2   = (u16*)(ws + 336244736);    // 384x192
    u16*   w3   = (u16*)(ws + 336392192);    // 1536x384
    u16*   w4   = (u16*)(ws + 337571840);    // 384x1536
    float* gp   = (float*)(ws + 338751488);  // 4x640 fp32
    float2* dwp = (float2*)(ws + 338761728); // 25x192 float2 (transposed)
    float* ktvp = (float*)(ws + 338800128);  // 192x4x272 fp32 partials

    prep<<<5885, 256, 0, stream>>>(proj_w, proj_g, proj_b, vp2_w, pw1_w, pw2_w,
                                   dw_w, w1p, w2, w3, w4, gp, dwp);
    transpose_x<<<dim3(16, 64, 6), 256, 0, stream>>>(x, xt);
    gemm_nhwc<1, 4, 4><<<2560, 256, 0, stream>>>(xt, w1p, proj, 384, 640, 5,
        gp, gp + 640, gp + 1280, gp + 1920, nullptr, es, rnd);
    attn_ktv<<<dim3(192, 4), 256, 0, stream>>>(proj, ktvp);
    attn_apply<<<dim3(192, 16), 256, 0, stream>>>(proj, ktvp, att);
    gemm_nhwc<2, 8, 4><<<768, 256, 0, stream>>>(att, w2, yt, 192, 384, 3,
        vp2_g, vp2_b, nullptr, nullptr, xt, rz_attn, nullptr);
    dwconv<<<dim3(64, 16), 192, 0, stream>>>(yt, dwp, dw_g, dw_b, z1);
    gemm_nhwc<3, 4, 8><<<3072, 256, 0, stream>>>(z1, w3, z2, 384, 1536, 6,
        pw1_g, pw1_b, nullptr, nullptr, nullptr, nullptr, nullptr);
    gemm_nhwc<4, 8, 4><<<768, 256, 0, stream>>>(z2, w4, z4, 1536, 384, 3,
        out_g, out_b, nullptr, nullptr, yt, rz_ffn, nullptr);
    transpose_out<<<dim3(16, 64, 6), 256, 0, stream>>>(z4, out);
}

// Round 5
// 692.502 us; speedup vs baseline: 1.2271x; 1.0106x over previous
//
#include <hip/hip_runtime.h>
#include <cstdint>

typedef unsigned short u16;
typedef __attribute__((ext_vector_type(8))) __bf16 bf16x8;
typedef __attribute__((ext_vector_type(4))) float f32x4;

__device__ __forceinline__ u16 f2bf(float f) {
    union { float f; uint32_t u; } v; v.f = f;
    uint32_t u = v.u;
    uint32_t r = (u + 0x7fffu + ((u >> 16) & 1u)) >> 16;
    return (u16)r;
}
__device__ __forceinline__ float bf2f(u16 h) {
    union { uint32_t u; float f; } v; v.u = ((uint32_t)h) << 16;
    return v.f;
}

// async global->LDS 16B per lane; LDS dest must be wave-uniform base + lane*16
__device__ __forceinline__ void ld_lds16(const u16* g, u16* l) {
    __builtin_amdgcn_global_load_lds(
        (const __attribute__((address_space(1))) uint32_t*)g,
        (__attribute__((address_space(3))) uint32_t*)l, 16, 0, 0);
}

// ---------------------------------------------------------------- prep ------
__global__ __launch_bounds__(256) void prep(
    const float* __restrict__ proj_w, const float* __restrict__ proj_g,
    const float* __restrict__ proj_b, const float* __restrict__ vp2_w,
    const float* __restrict__ pw1_w, const float* __restrict__ pw2_w,
    const float* __restrict__ dw_w,
    u16* __restrict__ w1p, u16* __restrict__ w2, u16* __restrict__ w3,
    u16* __restrict__ w4, float* __restrict__ gp, float2* __restrict__ dwp)
{
    int i = blockIdx.x * 256 + threadIdx.x;
    if (i < 245760) {                 // w1p: 640x384, rows >=576 zero
        int o = i / 384, k = i - o * 384;
        w1p[i] = (o < 576) ? f2bf(proj_w[o * 386 + k]) : (u16)0;
        return;
    }
    i -= 245760;
    if (i < 73728) { w2[i] = f2bf(vp2_w[i]); return; }   // 384x192
    i -= 73728;
    if (i < 589824) { w3[i] = f2bf(pw1_w[i]); return; }  // 1536x384
    i -= 589824;
    if (i < 589824) { w4[i] = f2bf(pw2_w[i]); return; }  // 384x1536
    i -= 589824;
    if (i < 2560) {                   // gp: [g1p|b1p|w1x|w1y] each 640 fp32
        int which = i / 640, o = i - which * 640;
        float v = 0.f;
        if (o < 576) {
            v = (which == 0) ? proj_g[o] : (which == 1) ? proj_b[o]
                : (which == 2) ? proj_w[o * 386 + 384] : proj_w[o * 386 + 385];
        }
        gp[i] = v; return;
    }
    i -= 2560;
    if (i < 4800) {                   // dwp TRANSPOSED: [tap 0..24][cp 0..191]
        int tap = i / 192, cp = i - tap * 192;
        dwp[i] = make_float2(dw_w[(2 * cp) * 25 + tap], dw_w[(2 * cp + 1) * 25 + tap]);
    }
}

// ------------------------------------------------- NCHW fp32 -> NHWC bf16 ---
__global__ __launch_bounds__(256) void transpose_x(const float* __restrict__ x,
                                                   u16* __restrict__ xt)
{
    __shared__ float tile[64][65];
    int b = blockIdx.x, n0 = blockIdx.y * 64, c0 = blockIdx.z * 64;
    int t = threadIdx.x;
    int jj = t & 63, i0 = t >> 6;
    #pragma unroll
    for (int r = 0; r < 16; r++) {
        int ci = r * 4 + i0;
        tile[ci][jj] = x[((size_t)b * 384 + c0 + ci) * 4096 + n0 + jj];
    }
    __syncthreads();
    #pragma unroll
    for (int r = 0; r < 16; r++) {
        int ni = r * 4 + i0;
        xt[(size_t)(b * 4096 + n0 + ni) * 384 + c0 + jj] = f2bf(tile[jj][ni]);
    }
}

// ------------------------------------------------- NHWC bf16 -> NCHW fp32 ---
__global__ __launch_bounds__(256) void transpose_out(const u16* __restrict__ zf,
                                                     float* __restrict__ out)
{
    __shared__ float tile[64][65];
    int b = blockIdx.x, n0 = blockIdx.y * 64, c0 = blockIdx.z * 64;
    int t = threadIdx.x;
    int jj = t & 63, i0 = t >> 6;
    #pragma unroll
    for (int r = 0; r < 16; r++) {
        int ni = r * 4 + i0;
        tile[ni][jj] = bf2f(zf[(size_t)(b * 4096 + n0 + ni) * 384 + c0 + jj]);
    }
    __syncthreads();
    #pragma unroll
    for (int r = 0; r < 16; r++) {
        int ci = r * 4 + i0;
        out[((size_t)b * 384 + c0 + ci) * 4096 + n0 + jj] = tile[jj][ci];
    }
}

// --------------------------------------------------------------- GEMM -------
// Out[pix][o] = epilogue( sum_k A[pix][k] * W[o][k] )   (both k-contiguous)
// v6: tile geometry templated; block = 2x2 waves of (IM*16)x(JN*16) tiles.
//   (4,4): NBUF=3 single-phase, counted vmcnt(4), distance-2 (proven r1 path).
//   fat (4,8)/(8,4): NBUF=2 TWO-PHASE counted pipeline — each K-iter splits
//     along the larger dim via even/odd 64-row staging chunks; waits are
//     vmcnt(NP1=2) / vmcnt(NP0=4), NEVER 0 in steady state, so prefetch DMAs
//     stay in flight across barriers (T3/T4).
// Epilogue: LDS bounce, stride BN+4 (16B-aligned rows), f32x4 reads
// (conflict-free) instead of 16 scalar reads (4-way conflicts).
template <int MODE, int IM, int JN>
__global__ __launch_bounds__(256) void gemm_nhwc(
    const u16* __restrict__ A, const u16* __restrict__ W,
    u16* __restrict__ out, int K, int Osz, int nOT,
    const float* __restrict__ g, const float* __restrict__ bb,
    const float* __restrict__ w1x, const float* __restrict__ w1y,
    const u16* __restrict__ res, const float* __restrict__ sc,
    const float* __restrict__ rnd)
{
    constexpr int BK = 32;
    constexpr int BM = IM * 32;
    constexpr int BN = JN * 32;
    constexpr int GA = IM / 2;        // 64-row staging chunks for A
    constexpr int GB = JN / 2;
    constexpr bool LEGACY = (IM == 4 && JN == 4);
    constexpr bool SPB = (JN >= IM);  // fat path: split along B (else A)
    constexpr int NBUF = LEGACY ? 3 : 2;
    constexpr int NP1 = LEGACY ? 0 : (SPB ? GB / 2 : GA / 2);   // ph1 chunks
    constexpr int NP0 = LEGACY ? 0 : (GA + GB - NP1);           // ph0 chunks
    __shared__ __align__(16) u16 smem[NBUF * (BM + BN) * BK];   // 48 KB

    const int tid = threadIdx.x;
    const int lane = tid & 63;
    const int wv = tid >> 6;
    const int wm = (wv >> 1) * (IM * 16);
    const int wn = (wv & 1) * (JN * 16);

    // bijective XCD chunking: nwg divisible by 8 in all launches
    const int nwg = gridDim.x;
    const int q8 = nwg >> 3;
    const int b1 = (blockIdx.x & 7) * q8 + (blockIdx.x >> 3);
    const int mt = b1 / nOT;
    const int ot = b1 - mt * nOT;
    const int m0 = mt * BM;
    const int o0 = ot * BN;

    const int q = lane >> 4;
    const int mr = lane & 15;
    // swizzled k-slot this lane READS: slot = q ^ ((row>>1)&3); row ≡ mr mod 16
    const int ks = (q ^ ((mr >> 1) & 3)) * 8;

    const int tq = tid >> 2;          // staging row 0..63 within chunk
    const int sl = tid & 3;           // linear LDS slot (dest is lane-linear)
    const int tk = (sl ^ ((tq >> 1) & 3)) * 8;   // swizzled GLOBAL k-chunk

    size_t ga[GA], gb[GB];
    int la[GA], lb[GB];
    #pragma unroll
    for (int gi = 0; gi < GA; gi++) {
        ga[gi] = (size_t)(m0 + gi * 64 + tq) * K + tk;
        la[gi] = (gi * 64 + tq) * BK + sl * 8;
    }
    #pragma unroll
    for (int gi = 0; gi < GB; gi++) {
        gb[gi] = (size_t)(o0 + gi * 64 + tq) * K + tk;
        lb[gi] = (gi * 64 + tq) * BK + sl * 8;
    }

    auto stage_all = [&](int tile, int bufi) {
        const size_t ko = (size_t)tile * BK;
        u16* sAb = smem + bufi * (BM * BK);
        u16* sBb = smem + NBUF * (BM * BK) + bufi * (BN * BK);
        #pragma unroll
        for (int gi = 0; gi < GA; gi++) ld_lds16(A + ga[gi] + ko, sAb + la[gi]);
        #pragma unroll
        for (int gi = 0; gi < GB; gi++) ld_lds16(W + gb[gi] + ko, sBb + lb[gi]);
    };
    auto stage_s0 = [&](int tile, int bufi) {   // even chunks of split dim
        const size_t ko = (size_t)tile * BK;
        u16* sAb = smem + bufi * (BM * BK);
        u16* sBb = smem + NBUF * (BM * BK) + bufi * (BN * BK);
        if constexpr (SPB) {
            #pragma unroll
            for (int gi = 0; gi < GA; gi++) ld_lds16(A + ga[gi] + ko, sAb + la[gi]);
            #pragma unroll
            for (int gi = 0; gi < GB; gi += 2) ld_lds16(W + gb[gi] + ko, sBb + lb[gi]);
        } else {
            #pragma unroll
            for (int gi = 0; gi < GA; gi += 2) ld_lds16(A + ga[gi] + ko, sAb + la[gi]);
            #pragma unroll
            for (int gi = 0; gi < GB; gi++) ld_lds16(W + gb[gi] + ko, sBb + lb[gi]);
        }
    };
    auto stage_s1 = [&](int tile, int bufi) {   // odd chunks of split dim
        const size_t ko = (size_t)tile * BK;
        u16* sAb = smem + bufi * (BM * BK);
        u16* sBb = smem + NBUF * (BM * BK) + bufi * (BN * BK);
        if constexpr (SPB) {
            #pragma unroll
            for (int gi = 1; gi < GB; gi += 2) ld_lds16(W + gb[gi] + ko, sBb + lb[gi]);
        } else {
            #pragma unroll
            for (int gi = 1; gi < GA; gi += 2) ld_lds16(A + ga[gi] + ko, sAb + la[gi]);
        }
    };

    f32x4 acc[IM][JN] = {};
    const int nIter = K >> 5;
    int buf = 0;

    if constexpr (LEGACY) {
        stage_all(0, 0);
        if (nIter > 1) stage_all(1, 1);
        for (int t = 0; t < nIter; ++t) {
            if (t + 1 < nIter) asm volatile("s_waitcnt vmcnt(4)" ::: "memory");
            else               asm volatile("s_waitcnt vmcnt(0)" ::: "memory");
            __builtin_amdgcn_s_barrier();
            __builtin_amdgcn_sched_barrier(0);
            if (t + 2 < nIter) {
                int nb = buf + 2; if (nb >= 3) nb -= 3;
                stage_all(t + 2, nb);
            }
            const u16* sAr = smem + buf * (BM * BK);
            const u16* sBr = smem + NBUF * (BM * BK) + buf * (BN * BK);
            bf16x8 af[IM], bfr[JN];
            #pragma unroll
            for (int i = 0; i < IM; i++)
                af[i] = *(const bf16x8*)&sAr[(wm + i * 16 + mr) * BK + ks];
            #pragma unroll
            for (int j = 0; j < JN; j++)
                bfr[j] = *(const bf16x8*)&sBr[(wn + j * 16 + mr) * BK + ks];
            __builtin_amdgcn_s_setprio(1);
            #pragma unroll
            for (int i = 0; i < IM; i++)
                #pragma unroll
                for (int j = 0; j < JN; j++)
                    acc[i][j] = __builtin_amdgcn_mfma_f32_16x16x32_bf16(af[i], bfr[j], acc[i][j], 0, 0, 0);
            __builtin_amdgcn_s_setprio(0);
            buf++; if (buf == 3) buf = 0;
        }
    } else {
        stage_s0(0, 0);
        stage_s1(0, 0);
        for (int t = 0; t < nIter; ++t) {
            const u16* sAr = smem + buf * (BM * BK);
            const u16* sBr = smem + NBUF * (BM * BK) + buf * (BN * BK);
            bf16x8 af[IM], bfr[JN];
            // ---------------- phase 0: S0(t) data ----------------
            asm volatile("s_waitcnt vmcnt(%0)" ::"i"(NP1) : "memory");
            __builtin_amdgcn_s_barrier();
            __builtin_amdgcn_sched_barrier(0);
            if constexpr (SPB) {
                #pragma unroll
                for (int i = 0; i < IM; i++)
                    af[i] = *(const bf16x8*)&sAr[(wm + i * 16 + mr) * BK + ks];
                #pragma unroll
                for (int j = 0; j < JN / 2; j++)
                    bfr[j] = *(const bf16x8*)&sBr[(wn + j * 16 + mr) * BK + ks];
            } else {
                #pragma unroll
                for (int i = 0; i < IM / 2; i++)
                    af[i] = *(const bf16x8*)&sAr[(wm + i * 16 + mr) * BK + ks];
                #pragma unroll
                for (int j = 0; j < JN; j++)
                    bfr[j] = *(const bf16x8*)&sBr[(wn + j * 16 + mr) * BK + ks];
            }
            if (t + 1 < nIter) stage_s0(t + 1, buf ^ 1);
            __builtin_amdgcn_s_setprio(1);
            if constexpr (SPB) {
                #pragma unroll
                for (int i = 0; i < IM; i++)
                    #pragma unroll
                    for (int j = 0; j < JN / 2; j++)
                        acc[i][j] = __builtin_amdgcn_mfma_f32_16x16x32_bf16(af[i], bfr[j], acc[i][j], 0, 0, 0);
            } else {
                #pragma unroll
                for (int i = 0; i < IM / 2; i++)
                    #pragma unroll
                    for (int j = 0; j < JN; j++)
                        acc[i][j] = __builtin_amdgcn_mfma_f32_16x16x32_bf16(af[i], bfr[j], acc[i][j], 0, 0, 0);
            }
            __builtin_amdgcn_s_setprio(0);
            // ---------------- phase 1: S1(t) data ----------------
            if (t + 1 < nIter)
                asm volatile("s_waitcnt vmcnt(%0)" ::"i"(NP0) : "memory");
            else
                asm volatile("s_waitcnt vmcnt(0)" ::: "memory");
            __builtin_amdgcn_s_barrier();
            __builtin_amdgcn_sched_barrier(0);
            if constexpr (SPB) {
                #pragma unroll
                for (int j = JN / 2; j < JN; j++)
                    bfr[j] = *(const bf16x8*)&sBr[(wn + j * 16 + mr) * BK + ks];
            } else {
                #pragma unroll
                for (int i = IM / 2; i < IM; i++)
                    af[i] = *(const bf16x8*)&sAr[(wm + i * 16 + mr) * BK + ks];
            }
            if (t + 1 < nIter) stage_s1(t + 1, buf ^ 1);
            __builtin_amdgcn_s_setprio(1);
            if constexpr (SPB) {
                #pragma unroll
                for (int i = 0; i < IM; i++)
                    #pragma unroll
                    for (int j = JN / 2; j < JN; j++)
                        acc[i][j] = __builtin_amdgcn_mfma_f32_16x16x32_bf16(af[i], bfr[j], acc[i][j], 0, 0, 0);
            } else {
                #pragma unroll
                for (int i = IM / 2; i < IM; i++)
                    #pragma unroll
                    for (int j = 0; j < JN; j++)
                        acc[i][j] = __builtin_amdgcn_mfma_f32_16x16x32_bf16(af[i], bfr[j], acc[i][j], 0, 0, 0);
            }
            __builtin_amdgcn_s_setprio(0);
            buf ^= 1;
        }
    }

    // -------- coalesced epilogue via LDS bounce (reuses smem) --------------
    float* st = (float*)smem;         // 32 x (BN+4) f32, rows 16B-aligned
    constexpr int LDE = BN + 4;
    constexpr int P = BM / 32;        // 32-row phases
    constexpr int HP = IM / 2;        // phases per wave-row-half
    constexpr int NG = BN / 128;      // 128-col groups
    const int row_l = tid >> 3;       // read phase: row 0..31
    const int cs16 = (tid & 7) * 16;  // read phase: 16-col segment

    float E = 0.f, offx = 0.f, offy = 0.f, rz = 0.f;
    if constexpr (MODE == 1) {
        E = expf(sc[0]);
        int bimg = m0 >> 12;
        offx = rnd[bimg * 2 + 0];
        offy = rnd[bimg * 2 + 1];
    }
    if constexpr (MODE == 2 || MODE == 4) rz = sc[0];

    float gv[NG][16], bv[NG][16];
    #pragma unroll
    for (int gg = 0; gg < NG; gg++)
        #pragma unroll
        for (int c = 0; c < 4; c++) {
            *(float4*)&gv[gg][c * 4] = *(const float4*)(g + o0 + gg * 128 + cs16 + c * 4);
            *(float4*)&bv[gg][c * 4] = *(const float4*)(bb + o0 + gg * 128 + cs16 + c * 4);
        }
    float wxv[16], wyv[16];
    if constexpr (MODE == 1) {        // MODE1 always uses NG==1 geometry
        #pragma unroll
        for (int c = 0; c < 4; c++) {
            *(float4*)&wxv[c * 4] = *(const float4*)(w1x + o0 + cs16 + c * 4);
            *(float4*)&wyv[c * 4] = *(const float4*)(w1y + o0 + cs16 + c * 4);
        }
    }

    #pragma unroll
    for (int p = 0; p < P; ++p) {
        __syncthreads();
        if ((wv >> 1) == p / HP) {    // 2 waves stage this 32-row slab
            const int ib = (p % HP) * 2;
            #pragma unroll
            for (int ii = 0; ii < 2; ++ii)
                #pragma unroll
                for (int j = 0; j < JN; ++j)
                    #pragma unroll
                    for (int r = 0; r < 4; ++r)
                        st[(ii * 16 + q * 4 + r) * LDE + wn + j * 16 + mr] =
                            acc[ib + ii][j][r];
        }
        __syncthreads();
        const int pix = m0 + p * 32 + row_l;
        float px = 0.f, py = 0.f;
        if constexpr (MODE == 1) {
            int n = pix & 4095;
            px = E * ((float)(n & 63) * 0.001f + offx);
            py = E * ((float)(n >> 6) * 0.001f + offy);
        }
        #pragma unroll
        for (int gg = 0; gg < NG; ++gg) {
            const int ob = o0 + gg * 128 + cs16;
            float vals[16];
            #pragma unroll
            for (int c = 0; c < 4; ++c)
                *(f32x4*)&vals[c * 4] =
                    *(const f32x4*)&st[row_l * LDE + gg * 128 + cs16 + c * 4];
            u16 rv[16];
            if constexpr (MODE == 2 || MODE == 4) {
                #pragma unroll
                for (int c = 0; c < 2; c++)
                    *(float4*)&rv[c * 8] = *(const float4*)(res + (size_t)pix * 384 + ob + c * 8);
            }
            u16 ov[16];
            #pragma unroll
            for (int e = 0; e < 16; ++e) {
                float v = vals[e];
                if constexpr (MODE == 1) {
                    v += px * wxv[e] + py * wyv[e];
                    v = fmaxf(gv[gg][e] * v + bv[gg][e], 0.f);
                } else if constexpr (MODE == 2) {
                    v = fmaxf(gv[gg][e] * v + bv[gg][e], 0.f);
                    v = bf2f(rv[e]) + rz * v;
                } else if constexpr (MODE == 3) {
                    float tv = gv[gg][e] * v + bv[gg][e];
                    v = tv * fminf(fmaxf(tv + 3.f, 0.f), 6.f) * (1.f / 6.f);
                } else {
                    float tv = gv[gg][e] * v + bv[gg][e];
                    v = bf2f(rv[e]) + rz * tv;
                }
                ov[e] = f2bf(v);
            }
            #pragma unroll
            for (int c = 0; c < 2; c++)
                *(float4*)(out + (size_t)pix * Osz + ob + c * 8) = *(const float4*)&ov[c * 8];
        }
    }
}

// ----------------------------------------------------------- attention ------
// Partial ktv over 4 N-chunks (768 blocks instead of 192 for occupancy);
// attn_apply sums the partials.
__global__ __launch_bounds__(256) void attn_ktv(const u16* __restrict__ proj,
                                                float* __restrict__ ktvp)
{
    int bh = blockIdx.x;
    int ch = blockIdx.y;
    int b = bh / 12, h = bh - b * 12;
    const u16* base = proj + (size_t)b * 4096 * 640;
    int kc = 192 + h * 16, vc = 384 + h * 16;
    __shared__ u16 ks[256 * 16];
    __shared__ u16 vs[256 * 16];
    int t = threadIdx.x;
    int d = t >> 4, e = t & 15;
    float acc = 0.f, ksum = 0.f;
    for (int n0 = ch * 1024; n0 < ch * 1024 + 1024; n0 += 256) {
        __syncthreads();
        const u16* r = base + (size_t)(n0 + t) * 640;
        ((float4*)&ks[t * 16])[0] = ((const float4*)(r + kc))[0];
        ((float4*)&ks[t * 16])[1] = ((const float4*)(r + kc))[1];
        ((float4*)&vs[t * 16])[0] = ((const float4*)(r + vc))[0];
        ((float4*)&vs[t * 16])[1] = ((const float4*)(r + vc))[1];
        __syncthreads();
        #pragma unroll 8
        for (int n = 0; n < 256; n++)
            acc += bf2f(ks[n * 16 + d]) * bf2f(vs[n * 16 + e]);
        if (t < 16) {
            #pragma unroll 8
            for (int n = 0; n < 256; n++) ksum += bf2f(ks[n * 16 + t]);
        }
    }
    float* o = ktvp + ((size_t)bh * 4 + ch) * 272;
    o[t] = acc;
    if (t < 16) o[256 + t] = ksum;
}

__global__ __launch_bounds__(256) void attn_apply(const u16* __restrict__ proj,
                                                  const float* __restrict__ ktvp,
                                                  u16* __restrict__ att)
{
    int bh = blockIdx.x;
    int b = bh / 12, h = bh - b * 12;
    __shared__ float kt[272];
    int t = threadIdx.x;
    {
        const float* p = ktvp + (size_t)bh * 4 * 272;
        kt[t] = p[t] + p[272 + t] + p[544 + t] + p[816 + t];
        if (t < 16) {
            int u = 256 + t;
            kt[u] = p[u] + p[272 + u] + p[544 + u] + p[816 + u];
        }
    }
    __syncthreads();
    int n = blockIdx.y * 256 + t;
    const u16* qr = proj + (size_t)(b * 4096 + n) * 640 + h * 16;
    float qv[16];
    #pragma unroll
    for (int d = 0; d < 16; d++) qv[d] = bf2f(qr[d]);
    float denom = 0.f;
    #pragma unroll
    for (int d = 0; d < 16; d++) denom += qv[d] * kt[256 + d];
    float rcp = 1.f / fmaxf(denom, 1e-4f);
    u16* op = att + (size_t)(b * 4096 + n) * 192 + h * 16;
    #pragma unroll
    for (int e = 0; e < 16; e++) {
        float s = 0.f;
        #pragma unroll
        for (int d = 0; d < 16; d++) s += qv[d] * kt[d * 16 + e];
        op[e] = f2bf(s * rcp);
    }
}

// -------------------------------------------------------- depthwise 5x5 -----
__global__ __launch_bounds__(192) void dwconv(const u16* __restrict__ y,
                                              const float2* __restrict__ wt,
                                              const float* __restrict__ g,
                                              const float* __restrict__ bc,
                                              u16* __restrict__ z)
{
    const int cp = threadIdx.x;        // 0..191
    const int xc = blockIdx.x;         // 0..63
    const int b  = blockIdx.y;         // 0..15
    const int c0 = cp * 2;

    float2 wv[25];
    #pragma unroll
    for (int t = 0; t < 25; t++) wv[t] = wt[t * 192 + cp];
    const float g0 = g[c0], g1 = g[c0 + 1];
    const float b0 = bc[c0], b1 = bc[c0 + 1];

    const size_t ibase = (size_t)b * 4096;
    const u16* ycol = y + ibase * 384 + c0;

    uint32_t r0[5], r1[5], r2[5], r3[5], r4[5];

#define LOADROW(yy, dst)                                                     \
    {                                                                        \
        if ((unsigned)(yy) < 64u) {                                          \
            const u16* rp = ycol + (size_t)(yy) * 64 * 384;                  \
            _Pragma("unroll")                                                \
            for (int dx = 0; dx < 5; dx++) {                                 \
                int xx = xc + dx - 2;                                        \
                dst[dx] = ((unsigned)xx < 64u)                               \
                              ? *(const uint32_t*)(rp + (size_t)xx * 384)    \
                              : 0u;                                          \
            }                                                                \
        } else {                                                             \
            _Pragma("unroll")                                                \
            for (int dx = 0; dx < 5; dx++) dst[dx] = 0u;                     \
        }                                                                    \
    }

#define COMPUTE(yr, A, B, C, D, E)                                           \
    if ((yr) < 64) {                                                         \
        float a0 = 0.f, a1 = 0.f;                                            \
        _Pragma("unroll")                                                    \
        for (int dx = 0; dx < 5; dx++) {                                     \
            uint32_t p;                                                      \
            p = A[dx];                                                       \
            a0 += wv[dx].x * bf2f((u16)(p & 0xffffu));                       \
            a1 += wv[dx].y * bf2f((u16)(p >> 16));                           \
            p = B[dx];                                                       \
            a0 += wv[5 + dx].x * bf2f((u16)(p & 0xffffu));                   \
            a1 += wv[5 + dx].y * bf2f((u16)(p >> 16));                       \
            p = C[dx];                                                       \
            a0 += wv[10 + dx].x * bf2f((u16)(p & 0xffffu));                  \
            a1 += wv[10 + dx].y * bf2f((u16)(p >> 16));                      \
            p = D[dx];                                                       \
            a0 += wv[15 + dx].x * bf2f((u16)(p & 0xffffu));                  \
            a1 += wv[15 + dx].y * bf2f((u16)(p >> 16));                      \
            p = E[dx];                                                       \
            a0 += wv[20 + dx].x * bf2f((u16)(p & 0xffffu));                  \
            a1 += wv[20 + dx].y * bf2f((u16)(p >> 16));                      \
        }                                                                    \
        float t0 = g0 * a0 + b0;                                             \
        float t1 = g1 * a1 + b1;                                             \
        t0 = t0 * fminf(fmaxf(t0 + 3.f, 0.f), 6.f) * (1.f / 6.f);            \
        t1 = t1 * fminf(fmaxf(t1 + 3.f, 0.f), 6.f) * (1.f / 6.f);            \
        uint32_t packed = (uint32_t)f2bf(t0) | ((uint32_t)f2bf(t1) << 16);   \
        *(uint32_t*)(z + (ibase + (size_t)(yr) * 64 + xc) * 384 + c0) = packed; \
    }

#define STEP(yr, A, B, C, D, E)                                              \
    COMPUTE(yr, A, B, C, D, E)                                               \
    LOADROW((yr) + 3, A)

    LOADROW(-2, r0)
    LOADROW(-1, r1)
    LOADROW(0, r2)
    LOADROW(1, r3)
    LOADROW(2, r4)

    for (int base = 0; base < 65; base += 5) {
        STEP(base + 0, r0, r1, r2, r3, r4)
        STEP(base + 1, r1, r2, r3, r4, r0)
        STEP(base + 2, r2, r3, r4, r0, r1)
        STEP(base + 3, r3, r4, r0, r1, r2)
        STEP(base + 4, r4, r0, r1, r2, r3)
    }
#undef STEP
#undef COMPUTE
#undef LOADROW
}

// ---------------------------------------------------------------------------
extern "C" void kernel_launch(void* const* d_in, const int* in_sizes, int n_in,
                              void* d_out, int out_size, void* d_ws, size_t ws_size,
                              hipStream_t stream)
{
    (void)in_sizes; (void)n_in; (void)out_size; (void)ws_size;
    const float* x       = (const float*)d_in[0];
    const float* rnd     = (const float*)d_in[1];
    const float* proj_w  = (const float*)d_in[2];
    const float* proj_g  = (const float*)d_in[3];
    const float* proj_b  = (const float*)d_in[4];
    const float* vp2_w   = (const float*)d_in[5];
    const float* vp2_g   = (const float*)d_in[6];
    const float* vp2_b   = (const float*)d_in[7];
    const float* dw_w    = (const float*)d_in[8];
    const float* dw_g    = (const float*)d_in[9];
    const float* dw_b    = (const float*)d_in[10];
    const float* pw1_w   = (const float*)d_in[11];
    const float* pw1_g   = (const float*)d_in[12];
    const float* pw1_b   = (const float*)d_in[13];
    const float* pw2_w   = (const float*)d_in[14];
    const float* out_g   = (const float*)d_in[15];
    const float* out_b   = (const float*)d_in[16];
    const float* rz_attn = (const float*)d_in[17];
    const float* rz_ffn  = (const float*)d_in[18];
    const float* es      = (const float*)d_in[19];
    float* out = (float*)d_out;

    char* ws = (char*)d_ws;
    u16*   xt   = (u16*)(ws + 0);            // 65536x384 bf16 (z2 aliases from 0)
    u16*   att  = (u16*)(ws + 50331648);     // 65536x192 bf16
    u16*   z2   = (u16*)(ws + 0);            // 65536x1536 bf16 (xt+att dead by then)
    u16*   proj = (u16*)(ws + 201326592);    // 65536x640 bf16
    u16*   z1   = proj;                      // 65536x384 (proj dead)
    u16*   z4   = proj;                      // 65536x384 (z1 dead)
    u16*   yt   = (u16*)(ws + 285212672);    // 65536x384 bf16
    u16*   w1p  = (u16*)(ws + 335753216);    // 640x384 bf16
    u16*   w2   = (u16*)(ws + 336244736);    // 384x192
    u16*   w3   = (u16*)(ws + 336392192);    // 1536x384
    u16*   w4   = (u16*)(ws + 337571840);    // 384x1536
    float* gp   = (float*)(ws + 338751488);  // 4x640 fp32
    float2* dwp = (float2*)(ws + 338761728); // 25x192 float2 (transposed)
    float* ktvp = (float*)(ws + 338800128);  // 192x4x272 fp32 partials

    prep<<<5885, 256, 0, stream>>>(proj_w, proj_g, proj_b, vp2_w, pw1_w, pw2_w,
                                   dw_w, w1p, w2, w3, w4, gp, dwp);
    transpose_x<<<dim3(16, 64, 6), 256, 0, stream>>>(x, xt);
    gemm_nhwc<1, 4, 4><<<2560, 256, 0, stream>>>(xt, w1p, proj, 384, 640, 5,
        gp, gp + 640, gp + 1280, gp + 1920, nullptr, es, rnd);
    attn_ktv<<<dim3(192, 4), 256, 0, stream>>>(proj, ktvp);
    attn_apply<<<dim3(192, 16), 256, 0, stream>>>(proj, ktvp, att);
    gemm_nhwc<2, 8, 4><<<768, 256, 0, stream>>>(att, w2, yt, 192, 384, 3,
        vp2_g, vp2_b, nullptr, nullptr, xt, rz_attn, nullptr);
    dwconv<<<dim3(64, 16), 192, 0, stream>>>(yt, dwp, dw_g, dw_b, z1);
    gemm_nhwc<3, 4, 8><<<3072, 256, 0, stream>>>(z1, w3, z2, 384, 1536, 6,
        pw1_g, pw1_b, nullptr, nullptr, nullptr, nullptr, nullptr);
    gemm_nhwc<4, 8, 4><<<768, 256, 0, stream>>>(z2, w4, z4, 1536, 384, 3,
        out_g, out_b, nullptr, nullptr, yt, rz_ffn, nullptr);
    transpose_out<<<dim3(16, 64, 6), 256, 0, stream>>>(z4, out);
}

// Round 6
// 666.437 us; speedup vs baseline: 1.2750x; 1.0391x over previous
//
#include <hip/hip_runtime.h>
#include <cstdint>

typedef unsigned short u16;
typedef __attribute__((ext_vector_type(8))) __bf16 bf16x8;
typedef __attribute__((ext_vector_type(4))) float f32x4;

__device__ __forceinline__ u16 f2bf(float f) {
    union { float f; uint32_t u; } v; v.f = f;
    uint32_t u = v.u;
    uint32_t r = (u + 0x7fffu + ((u >> 16) & 1u)) >> 16;
    return (u16)r;
}
__device__ __forceinline__ float bf2f(u16 h) {
    union { uint32_t u; float f; } v; v.u = ((uint32_t)h) << 16;
    return v.f;
}
__device__ __forceinline__ float bflo(uint32_t u) {
    union { uint32_t u; float f; } v; v.u = u << 16;
    return v.f;
}
__device__ __forceinline__ float bfhi(uint32_t u) {
    union { uint32_t u; float f; } v; v.u = u & 0xffff0000u;
    return v.f;
}

// async global->LDS 16B per lane; LDS dest must be wave-uniform base + lane*16
__device__ __forceinline__ void ld_lds16(const u16* g, u16* l) {
    __builtin_amdgcn_global_load_lds(
        (const __attribute__((address_space(1))) uint32_t*)g,
        (__attribute__((address_space(3))) uint32_t*)l, 16, 0, 0);
}

// ---------------------------------------------------------------- prep ------
__global__ __launch_bounds__(256) void prep(
    const float* __restrict__ proj_w, const float* __restrict__ proj_g,
    const float* __restrict__ proj_b, const float* __restrict__ vp2_w,
    const float* __restrict__ pw1_w, const float* __restrict__ pw2_w,
    const float* __restrict__ dw_w,
    u16* __restrict__ w1p, u16* __restrict__ w2, u16* __restrict__ w3,
    u16* __restrict__ w4, float* __restrict__ gp, float2* __restrict__ dwp)
{
    int i = blockIdx.x * 256 + threadIdx.x;
    if (i < 245760) {                 // w1p: 640x384, rows >=576 zero
        int o = i / 384, k = i - o * 384;
        w1p[i] = (o < 576) ? f2bf(proj_w[o * 386 + k]) : (u16)0;
        return;
    }
    i -= 245760;
    if (i < 73728) { w2[i] = f2bf(vp2_w[i]); return; }   // 384x192
    i -= 73728;
    if (i < 589824) { w3[i] = f2bf(pw1_w[i]); return; }  // 1536x384
    i -= 589824;
    if (i < 589824) { w4[i] = f2bf(pw2_w[i]); return; }  // 384x1536
    i -= 589824;
    if (i < 2560) {                   // gp: [g1p|b1p|w1x|w1y] each 640 fp32
        int which = i / 640, o = i - which * 640;
        float v = 0.f;
        if (o < 576) {
            v = (which == 0) ? proj_g[o] : (which == 1) ? proj_b[o]
                : (which == 2) ? proj_w[o * 386 + 384] : proj_w[o * 386 + 385];
        }
        gp[i] = v; return;
    }
    i -= 2560;
    if (i < 4800) {                   // dwp TRANSPOSED: [tap 0..24][cp 0..191]
        int tap = i / 192, cp = i - tap * 192;
        dwp[i] = make_float2(dw_w[(2 * cp) * 25 + tap], dw_w[(2 * cp + 1) * 25 + tap]);
    }
}

// ------------------------------------------------- NCHW fp32 -> NHWC bf16 ---
__global__ __launch_bounds__(256) void transpose_x(const float* __restrict__ x,
                                                   u16* __restrict__ xt)
{
    __shared__ float tile[64][65];
    int b = blockIdx.x, n0 = blockIdx.y * 64, c0 = blockIdx.z * 64;
    int t = threadIdx.x;
    int jj = t & 63, i0 = t >> 6;
    #pragma unroll
    for (int r = 0; r < 16; r++) {
        int ci = r * 4 + i0;
        tile[ci][jj] = x[((size_t)b * 384 + c0 + ci) * 4096 + n0 + jj];
    }
    __syncthreads();
    #pragma unroll
    for (int r = 0; r < 16; r++) {
        int ni = r * 4 + i0;
        xt[(size_t)(b * 4096 + n0 + ni) * 384 + c0 + jj] = f2bf(tile[jj][ni]);
    }
}

// --------------------------------------------------------------- GEMM -------
// Out[pix][o] = epilogue( sum_k A[pix][k] * W[o][k] )   (both k-contiguous)
// v7: tile geometry templated; block = 2x2 waves of (IM*16)x(JN*16) tiles.
//   (4,4): NBUF=3 single-phase, counted vmcnt(4), distance-2.
//   fat (4,8)/(8,4): NBUF=2 two-phase counted (vmcnt NP1/NP0, never 0 steady).
// OUTT=1 (requires BN=128): epilogue emits fp32 NCHW directly (fused
// transpose_out) — row-pass computes fp32 into LDS, col-pass writes 64B/lane
// contiguous per channel. Saves the separate 450 MB transpose kernel.
template <int MODE, int IM, int JN, int OUTT>
__global__ __launch_bounds__(256) void gemm_nhwc(
    const u16* __restrict__ A, const u16* __restrict__ W,
    u16* __restrict__ out, int K, int Osz, int nOT,
    const float* __restrict__ g, const float* __restrict__ bb,
    const float* __restrict__ w1x, const float* __restrict__ w1y,
    const u16* __restrict__ res, const float* __restrict__ sc,
    const float* __restrict__ rnd)
{
    constexpr int BK = 32;
    constexpr int BM = IM * 32;
    constexpr int BN = JN * 32;
    constexpr int GA = IM / 2;        // 64-row staging chunks for A
    constexpr int GB = JN / 2;
    constexpr bool LEGACY = (IM == 4 && JN == 4);
    constexpr bool SPB = (JN >= IM);  // fat path: split along B (else A)
    constexpr int NBUF = LEGACY ? 3 : 2;
    constexpr int NP1 = LEGACY ? 0 : (SPB ? GB / 2 : GA / 2);   // ph1 chunks
    constexpr int NP0 = LEGACY ? 0 : (GA + GB - NP1);           // ph0 chunks
    __shared__ __align__(16) u16 smem[NBUF * (BM + BN) * BK];   // 48 KB

    const int tid = threadIdx.x;
    const int lane = tid & 63;
    const int wv = tid >> 6;
    const int wm = (wv >> 1) * (IM * 16);
    const int wn = (wv & 1) * (JN * 16);

    // bijective XCD chunking: nwg divisible by 8 in all launches
    const int nwg = gridDim.x;
    const int q8 = nwg >> 3;
    const int b1 = (blockIdx.x & 7) * q8 + (blockIdx.x >> 3);
    const int mt = b1 / nOT;
    const int ot = b1 - mt * nOT;
    const int m0 = mt * BM;
    const int o0 = ot * BN;

    const int q = lane >> 4;
    const int mr = lane & 15;
    // swizzled k-slot this lane READS: slot = q ^ ((row>>1)&3); row ≡ mr mod 16
    const int ks = (q ^ ((mr >> 1) & 3)) * 8;

    const int tq = tid >> 2;          // staging row 0..63 within chunk
    const int sl = tid & 3;           // linear LDS slot (dest is lane-linear)
    const int tk = (sl ^ ((tq >> 1) & 3)) * 8;   // swizzled GLOBAL k-chunk

    size_t ga[GA], gb[GB];
    int la[GA], lb[GB];
    #pragma unroll
    for (int gi = 0; gi < GA; gi++) {
        ga[gi] = (size_t)(m0 + gi * 64 + tq) * K + tk;
        la[gi] = (gi * 64 + tq) * BK + sl * 8;
    }
    #pragma unroll
    for (int gi = 0; gi < GB; gi++) {
        gb[gi] = (size_t)(o0 + gi * 64 + tq) * K + tk;
        lb[gi] = (gi * 64 + tq) * BK + sl * 8;
    }

    auto stage_all = [&](int tile, int bufi) {
        const size_t ko = (size_t)tile * BK;
        u16* sAb = smem + bufi * (BM * BK);
        u16* sBb = smem + NBUF * (BM * BK) + bufi * (BN * BK);
        #pragma unroll
        for (int gi = 0; gi < GA; gi++) ld_lds16(A + ga[gi] + ko, sAb + la[gi]);
        #pragma unroll
        for (int gi = 0; gi < GB; gi++) ld_lds16(W + gb[gi] + ko, sBb + lb[gi]);
    };
    auto stage_s0 = [&](int tile, int bufi) {   // even chunks of split dim
        const size_t ko = (size_t)tile * BK;
        u16* sAb = smem + bufi * (BM * BK);
        u16* sBb = smem + NBUF * (BM * BK) + bufi * (BN * BK);
        if constexpr (SPB) {
            #pragma unroll
            for (int gi = 0; gi < GA; gi++) ld_lds16(A + ga[gi] + ko, sAb + la[gi]);
            #pragma unroll
            for (int gi = 0; gi < GB; gi += 2) ld_lds16(W + gb[gi] + ko, sBb + lb[gi]);
        } else {
            #pragma unroll
            for (int gi = 0; gi < GA; gi += 2) ld_lds16(A + ga[gi] + ko, sAb + la[gi]);
            #pragma unroll
            for (int gi = 0; gi < GB; gi++) ld_lds16(W + gb[gi] + ko, sBb + lb[gi]);
        }
    };
    auto stage_s1 = [&](int tile, int bufi) {   // odd chunks of split dim
        const size_t ko = (size_t)tile * BK;
        u16* sAb = smem + bufi * (BM * BK);
        u16* sBb = smem + NBUF * (BM * BK) + bufi * (BN * BK);
        if constexpr (SPB) {
            #pragma unroll
            for (int gi = 1; gi < GB; gi += 2) ld_lds16(W + gb[gi] + ko, sBb + lb[gi]);
        } else {
            #pragma unroll
            for (int gi = 1; gi < GA; gi += 2) ld_lds16(A + ga[gi] + ko, sAb + la[gi]);
        }
    };

    f32x4 acc[IM][JN] = {};
    const int nIter = K >> 5;
    int buf = 0;

    if constexpr (LEGACY) {
        stage_all(0, 0);
        if (nIter > 1) stage_all(1, 1);
        for (int t = 0; t < nIter; ++t) {
            if (t + 1 < nIter) asm volatile("s_waitcnt vmcnt(4)" ::: "memory");
            else               asm volatile("s_waitcnt vmcnt(0)" ::: "memory");
            __builtin_amdgcn_s_barrier();
            __builtin_amdgcn_sched_barrier(0);
            if (t + 2 < nIter) {
                int nb = buf + 2; if (nb >= 3) nb -= 3;
                stage_all(t + 2, nb);
            }
            const u16* sAr = smem + buf * (BM * BK);
            const u16* sBr = smem + NBUF * (BM * BK) + buf * (BN * BK);
            bf16x8 af[IM], bfr[JN];
            #pragma unroll
            for (int i = 0; i < IM; i++)
                af[i] = *(const bf16x8*)&sAr[(wm + i * 16 + mr) * BK + ks];
            #pragma unroll
            for (int j = 0; j < JN; j++)
                bfr[j] = *(const bf16x8*)&sBr[(wn + j * 16 + mr) * BK + ks];
            __builtin_amdgcn_s_setprio(1);
            #pragma unroll
            for (int i = 0; i < IM; i++)
                #pragma unroll
                for (int j = 0; j < JN; j++)
                    acc[i][j] = __builtin_amdgcn_mfma_f32_16x16x32_bf16(af[i], bfr[j], acc[i][j], 0, 0, 0);
            __builtin_amdgcn_s_setprio(0);
            buf++; if (buf == 3) buf = 0;
        }
    } else {
        stage_s0(0, 0);
        stage_s1(0, 0);
        for (int t = 0; t < nIter; ++t) {
            const u16* sAr = smem + buf * (BM * BK);
            const u16* sBr = smem + NBUF * (BM * BK) + buf * (BN * BK);
            bf16x8 af[IM], bfr[JN];
            // ---------------- phase 0: S0(t) data ----------------
            asm volatile("s_waitcnt vmcnt(%0)" ::"i"(NP1) : "memory");
            __builtin_amdgcn_s_barrier();
            __builtin_amdgcn_sched_barrier(0);
            if constexpr (SPB) {
                #pragma unroll
                for (int i = 0; i < IM; i++)
                    af[i] = *(const bf16x8*)&sAr[(wm + i * 16 + mr) * BK + ks];
                #pragma unroll
                for (int j = 0; j < JN / 2; j++)
                    bfr[j] = *(const bf16x8*)&sBr[(wn + j * 16 + mr) * BK + ks];
            } else {
                #pragma unroll
                for (int i = 0; i < IM / 2; i++)
                    af[i] = *(const bf16x8*)&sAr[(wm + i * 16 + mr) * BK + ks];
                #pragma unroll
                for (int j = 0; j < JN; j++)
                    bfr[j] = *(const bf16x8*)&sBr[(wn + j * 16 + mr) * BK + ks];
            }
            if (t + 1 < nIter) stage_s0(t + 1, buf ^ 1);
            __builtin_amdgcn_s_setprio(1);
            if constexpr (SPB) {
                #pragma unroll
                for (int i = 0; i < IM; i++)
                    #pragma unroll
                    for (int j = 0; j < JN / 2; j++)
                        acc[i][j] = __builtin_amdgcn_mfma_f32_16x16x32_bf16(af[i], bfr[j], acc[i][j], 0, 0, 0);
            } else {
                #pragma unroll
                for (int i = 0; i < IM / 2; i++)
                    #pragma unroll
                    for (int j = 0; j < JN; j++)
                        acc[i][j] = __builtin_amdgcn_mfma_f32_16x16x32_bf16(af[i], bfr[j], acc[i][j], 0, 0, 0);
            }
            __builtin_amdgcn_s_setprio(0);
            // ---------------- phase 1: S1(t) data ----------------
            if (t + 1 < nIter)
                asm volatile("s_waitcnt vmcnt(%0)" ::"i"(NP0) : "memory");
            else
                asm volatile("s_waitcnt vmcnt(0)" ::: "memory");
            __builtin_amdgcn_s_barrier();
            __builtin_amdgcn_sched_barrier(0);
            if constexpr (SPB) {
                #pragma unroll
                for (int j = JN / 2; j < JN; j++)
                    bfr[j] = *(const bf16x8*)&sBr[(wn + j * 16 + mr) * BK + ks];
            } else {
                #pragma unroll
                for (int i = IM / 2; i < IM; i++)
                    af[i] = *(const bf16x8*)&sAr[(wm + i * 16 + mr) * BK + ks];
            }
            if (t + 1 < nIter) stage_s1(t + 1, buf ^ 1);
            __builtin_amdgcn_s_setprio(1);
            if constexpr (SPB) {
                #pragma unroll
                for (int i = 0; i < IM; i++)
                    #pragma unroll
                    for (int j = JN / 2; j < JN; j++)
                        acc[i][j] = __builtin_amdgcn_mfma_f32_16x16x32_bf16(af[i], bfr[j], acc[i][j], 0, 0, 0);
            } else {
                #pragma unroll
                for (int i = IM / 2; i < IM; i++)
                    #pragma unroll
                    for (int j = 0; j < JN; j++)
                        acc[i][j] = __builtin_amdgcn_mfma_f32_16x16x32_bf16(af[i], bfr[j], acc[i][j], 0, 0, 0);
            }
            __builtin_amdgcn_s_setprio(0);
            buf ^= 1;
        }
    }

    // -------- coalesced epilogue via LDS bounce (reuses smem) --------------
    float* st = (float*)smem;         // 32 x (BN+4) f32, rows 16B-aligned
    constexpr int LDE = BN + 4;
    constexpr int P = BM / 32;        // 32-row phases
    constexpr int HP = IM / 2;        // phases per wave-row-half
    constexpr int NG = BN / 128;      // 128-col groups
    const int row_l = tid >> 3;       // read phase: row 0..31
    const int cs16 = (tid & 7) * 16;  // read phase: 16-col segment

    float E = 0.f, offx = 0.f, offy = 0.f, rz = 0.f;
    if constexpr (MODE == 1) {
        E = expf(sc[0]);
        int bimg = m0 >> 12;
        offx = rnd[bimg * 2 + 0];
        offy = rnd[bimg * 2 + 1];
    }
    if constexpr (MODE == 2 || MODE == 4) rz = sc[0];

    float gv[NG][16], bv[NG][16];
    #pragma unroll
    for (int gg = 0; gg < NG; gg++)
        #pragma unroll
        for (int c = 0; c < 4; c++) {
            *(float4*)&gv[gg][c * 4] = *(const float4*)(g + o0 + gg * 128 + cs16 + c * 4);
            *(float4*)&bv[gg][c * 4] = *(const float4*)(bb + o0 + gg * 128 + cs16 + c * 4);
        }
    float wxv[16], wyv[16];
    if constexpr (MODE == 1) {        // MODE1 always uses NG==1 geometry
        #pragma unroll
        for (int c = 0; c < 4; c++) {
            *(float4*)&wxv[c * 4] = *(const float4*)(w1x + o0 + cs16 + c * 4);
            *(float4*)&wyv[c * 4] = *(const float4*)(w1y + o0 + cs16 + c * 4);
        }
    }

    #pragma unroll
    for (int p = 0; p < P; ++p) {
        __syncthreads();
        if ((wv >> 1) == p / HP) {    // 2 waves stage this 32-row slab
            const int ib = (p % HP) * 2;
            #pragma unroll
            for (int ii = 0; ii < 2; ++ii)
                #pragma unroll
                for (int j = 0; j < JN; ++j)
                    #pragma unroll
                    for (int r = 0; r < 4; ++r)
                        st[(ii * 16 + q * 4 + r) * LDE + wn + j * 16 + mr] =
                            acc[ib + ii][j][r];
        }
        __syncthreads();
        const int pix = m0 + p * 32 + row_l;
        float px = 0.f, py = 0.f;
        if constexpr (MODE == 1) {
            int n = pix & 4095;
            px = E * ((float)(n & 63) * 0.001f + offx);
            py = E * ((float)(n >> 6) * 0.001f + offy);
        }
        #pragma unroll
        for (int gg = 0; gg < NG; ++gg) {
            const int ob = o0 + gg * 128 + cs16;
            float vals[16];
            #pragma unroll
            for (int c = 0; c < 4; ++c)
                *(f32x4*)&vals[c * 4] =
                    *(const f32x4*)&st[row_l * LDE + gg * 128 + cs16 + c * 4];
            u16 rv[16];
            if constexpr (MODE == 2 || MODE == 4) {
                #pragma unroll
                for (int c = 0; c < 2; c++)
                    *(float4*)&rv[c * 8] = *(const float4*)(res + (size_t)pix * 384 + ob + c * 8);
            }
            float fv[16];
            #pragma unroll
            for (int e = 0; e < 16; ++e) {
                float v = vals[e];
                if constexpr (MODE == 1) {
                    v += px * wxv[e] + py * wyv[e];
                    v = fmaxf(gv[gg][e] * v + bv[gg][e], 0.f);
                } else if constexpr (MODE == 2) {
                    v = fmaxf(gv[gg][e] * v + bv[gg][e], 0.f);
                    v = bf2f(rv[e]) + rz * v;
                } else if constexpr (MODE == 3) {
                    float tv = gv[gg][e] * v + bv[gg][e];
                    v = tv * fminf(fmaxf(tv + 3.f, 0.f), 6.f) * (1.f / 6.f);
                } else {
                    float tv = gv[gg][e] * v + bv[gg][e];
                    v = bf2f(rv[e]) + rz * tv;
                }
                fv[e] = v;
            }
            if constexpr (OUTT) {
                // write fp32 back in place; col-pass emits NCHW
                #pragma unroll
                for (int c = 0; c < 4; ++c)
                    *(f32x4*)&st[row_l * LDE + gg * 128 + cs16 + c * 4] =
                        *(const f32x4*)&fv[c * 4];
            } else {
                u16 ov[16];
                #pragma unroll
                for (int e = 0; e < 16; ++e) ov[e] = f2bf(fv[e]);
                #pragma unroll
                for (int c = 0; c < 2; c++)
                    *(float4*)(out + (size_t)pix * Osz + ob + c * 8) = *(const float4*)&ov[c * 8];
            }
        }
        if constexpr (OUTT) {         // BN==128: fused NCHW fp32 transpose-out
            __syncthreads();
            const int cl = tid & 127;
            const int rh = tid >> 7;  // 0/1 -> rows rh*16..rh*16+15
            const int pixb = m0 + p * 32;
            const int bimg2 = pixb >> 12;
            const int n0 = (pixb & 4095) + rh * 16;
            float tv[16];
            #pragma unroll
            for (int k2 = 0; k2 < 16; ++k2)
                tv[k2] = st[(rh * 16 + k2) * LDE + cl];
            float* dst = (float*)out + ((size_t)bimg2 * 384 + o0 + cl) * 4096 + n0;
            #pragma unroll
            for (int c = 0; c < 4; c++)
                *(float4*)(dst + c * 4) = *(const float4*)&tv[c * 4];
        }
    }
}

// ----------------------------------------------------------- attention ------
// ktv: K,V staged TRANSPOSED in LDS ([16][264]) so the inner MAC uses 16B
// vector reads (broadcast across lanes) instead of 512 scalar u16 reads.
__global__ __launch_bounds__(256) void attn_ktv(const u16* __restrict__ proj,
                                                float* __restrict__ ktvp)
{
    constexpr int LDT = 264;          // u16 stride (528 B, 16B-aligned)
    __shared__ u16 kt_[16 * LDT];
    __shared__ u16 vt_[16 * LDT];
    int bh = blockIdx.x;
    int ch = blockIdx.y;
    int b = bh / 12, h = bh - b * 12;
    const u16* base = proj + (size_t)b * 4096 * 640;
    int kc = 192 + h * 16, vc = 384 + h * 16;
    int t = threadIdx.x;
    int d = t >> 4, e = t & 15;
    float acc = 0.f, ksum = 0.f;
    for (int n0 = ch * 1024; n0 < ch * 1024 + 1024; n0 += 256) {
        __syncthreads();
        const u16* r = base + (size_t)(n0 + t) * 640;
        u16 kv[16], vv[16];
        *(float4*)&kv[0] = ((const float4*)(r + kc))[0];
        *(float4*)&kv[8] = ((const float4*)(r + kc))[1];
        *(float4*)&vv[0] = ((const float4*)(r + vc))[0];
        *(float4*)&vv[8] = ((const float4*)(r + vc))[1];
        #pragma unroll
        for (int dd = 0; dd < 16; dd++) {
            kt_[dd * LDT + t] = kv[dd];
            vt_[dd * LDT + t] = vv[dd];
        }
        __syncthreads();
        const u16* kr = &kt_[d * LDT];
        const u16* vr = &vt_[e * LDT];
        #pragma unroll 4
        for (int n = 0; n < 256; n += 8) {
            uint4 kw = *(const uint4*)(kr + n);
            uint4 vw = *(const uint4*)(vr + n);
            acc += bflo(kw.x) * bflo(vw.x) + bfhi(kw.x) * bfhi(vw.x);
            acc += bflo(kw.y) * bflo(vw.y) + bfhi(kw.y) * bfhi(vw.y);
            acc += bflo(kw.z) * bflo(vw.z) + bfhi(kw.z) * bfhi(vw.z);
            acc += bflo(kw.w) * bflo(vw.w) + bfhi(kw.w) * bfhi(vw.w);
        }
        if (t < 16) {
            const u16* krs = &kt_[t * LDT];
            #pragma unroll 4
            for (int n = 0; n < 256; n += 8) {
                uint4 kw = *(const uint4*)(krs + n);
                ksum += bflo(kw.x) + bfhi(kw.x) + bflo(kw.y) + bfhi(kw.y)
                      + bflo(kw.z) + bfhi(kw.z) + bflo(kw.w) + bfhi(kw.w);
            }
        }
    }
    float* o = ktvp + ((size_t)bh * 4 + ch) * 272;
    o[t] = acc;
    if (t < 16) o[256 + t] = ksum;
}

__global__ __launch_bounds__(256) void attn_apply(const u16* __restrict__ proj,
                                                  const float* __restrict__ ktvp,
                                                  u16* __restrict__ att)
{
    int bh = blockIdx.x;
    int b = bh / 12, h = bh - b * 12;
    __shared__ float kt[272];
    int t = threadIdx.x;
    {
        const float* p = ktvp + (size_t)bh * 4 * 272;
        kt[t] = p[t] + p[272 + t] + p[544 + t] + p[816 + t];
        if (t < 16) {
            int u = 256 + t;
            kt[u] = p[u] + p[272 + u] + p[544 + u] + p[816 + u];
        }
    }
    __syncthreads();
    int n = blockIdx.y * 256 + t;
    const u16* qr = proj + (size_t)(b * 4096 + n) * 640 + h * 16;
    u16 qb[16];
    *(float4*)&qb[0] = ((const float4*)qr)[0];
    *(float4*)&qb[8] = ((const float4*)qr)[1];
    float qv[16];
    #pragma unroll
    for (int d = 0; d < 16; d++) qv[d] = bf2f(qb[d]);
    float denom = 0.f;
    #pragma unroll
    for (int d = 0; d < 16; d++) denom += qv[d] * kt[256 + d];
    float rcp = 1.f / fmaxf(denom, 1e-4f);
    u16* op = att + (size_t)(b * 4096 + n) * 192 + h * 16;
    u16 ov[16];
    #pragma unroll
    for (int e = 0; e < 16; e++) {
        float s = 0.f;
        #pragma unroll
        for (int d = 0; d < 16; d++) s += qv[d] * kt[d * 16 + e];
        ov[e] = f2bf(s * rcp);
    }
    ((float4*)op)[0] = *(const float4*)&ov[0];
    ((float4*)op)[1] = *(const float4*)&ov[8];
}

// -------------------------------------------------------- depthwise 5x5 -----
__global__ __launch_bounds__(192) void dwconv(const u16* __restrict__ y,
                                              const float2* __restrict__ wt,
                                              const float* __restrict__ g,
                                              const float* __restrict__ bc,
                                              u16* __restrict__ z)
{
    const int cp = threadIdx.x;        // 0..191
    const int xc = blockIdx.x;         // 0..63
    const int b  = blockIdx.y;         // 0..15
    const int c0 = cp * 2;

    float2 wv[25];
    #pragma unroll
    for (int t = 0; t < 25; t++) wv[t] = wt[t * 192 + cp];
    const float g0 = g[c0], g1 = g[c0 + 1];
    const float b0 = bc[c0], b1 = bc[c0 + 1];

    const size_t ibase = (size_t)b * 4096;
    const u16* ycol = y + ibase * 384 + c0;

    uint32_t r0[5], r1[5], r2[5], r3[5], r4[5];

#define LOADROW(yy, dst)                                                     \
    {                                                                        \
        if ((unsigned)(yy) < 64u) {                                          \
            const u16* rp = ycol + (size_t)(yy) * 64 * 384;                  \
            _Pragma("unroll")                                                \
            for (int dx = 0; dx < 5; dx++) {                                 \
                int xx = xc + dx - 2;                                        \
                dst[dx] = ((unsigned)xx < 64u)                               \
                              ? *(const uint32_t*)(rp + (size_t)xx * 384)    \
                              : 0u;                                          \
            }                                                                \
        } else {                                                             \
            _Pragma("unroll")                                                \
            for (int dx = 0; dx < 5; dx++) dst[dx] = 0u;                     \
        }                                                                    \
    }

#define COMPUTE(yr, A, B, C, D, E)                                           \
    if ((yr) < 64) {                                                         \
        float a0 = 0.f, a1 = 0.f;                                            \
        _Pragma("unroll")                                                    \
        for (int dx = 0; dx < 5; dx++) {                                     \
            uint32_t p;                                                      \
            p = A[dx];                                                       \
            a0 += wv[dx].x * bf2f((u16)(p & 0xffffu));                       \
            a1 += wv[dx].y * bf2f((u16)(p >> 16));                           \
            p = B[dx];                                                       \
            a0 += wv[5 + dx].x * bf2f((u16)(p & 0xffffu));                   \
            a1 += wv[5 + dx].y * bf2f((u16)(p >> 16));                       \
            p = C[dx];                                                       \
            a0 += wv[10 + dx].x * bf2f((u16)(p & 0xffffu));                  \
            a1 += wv[10 + dx].y * bf2f((u16)(p >> 16));                      \
            p = D[dx];                                                       \
            a0 += wv[15 + dx].x * bf2f((u16)(p & 0xffffu));                  \
            a1 += wv[15 + dx].y * bf2f((u16)(p >> 16));                      \
            p = E[dx];                                                       \
            a0 += wv[20 + dx].x * bf2f((u16)(p & 0xffffu));                  \
            a1 += wv[20 + dx].y * bf2f((u16)(p >> 16));                      \
        }                                                                    \
        float t0 = g0 * a0 + b0;                                             \
        float t1 = g1 * a1 + b1;                                             \
        t0 = t0 * fminf(fmaxf(t0 + 3.f, 0.f), 6.f) * (1.f / 6.f);            \
        t1 = t1 * fminf(fmaxf(t1 + 3.f, 0.f), 6.f) * (1.f / 6.f);            \
        uint32_t packed = (uint32_t)f2bf(t0) | ((uint32_t)f2bf(t1) << 16);   \
        *(uint32_t*)(z + (ibase + (size_t)(yr) * 64 + xc) * 384 + c0) = packed; \
    }

#define STEP(yr, A, B, C, D, E)                                              \
    COMPUTE(yr, A, B, C, D, E)                                               \
    LOADROW((yr) + 3, A)

    LOADROW(-2, r0)
    LOADROW(-1, r1)
    LOADROW(0, r2)
    LOADROW(1, r3)
    LOADROW(2, r4)

    for (int base = 0; base < 65; base += 5) {
        STEP(base + 0, r0, r1, r2, r3, r4)
        STEP(base + 1, r1, r2, r3, r4, r0)
        STEP(base + 2, r2, r3, r4, r0, r1)
        STEP(base + 3, r3, r4, r0, r1, r2)
        STEP(base + 4, r4, r0, r1, r2, r3)
    }
#undef STEP
#undef COMPUTE
#undef LOADROW
}

// ---------------------------------------------------------------------------
extern "C" void kernel_launch(void* const* d_in, const int* in_sizes, int n_in,
                              void* d_out, int out_size, void* d_ws, size_t ws_size,
                              hipStream_t stream)
{
    (void)in_sizes; (void)n_in; (void)out_size; (void)ws_size;
    const float* x       = (const float*)d_in[0];
    const float* rnd     = (const float*)d_in[1];
    const float* proj_w  = (const float*)d_in[2];
    const float* proj_g  = (const float*)d_in[3];
    const float* proj_b  = (const float*)d_in[4];
    const float* vp2_w   = (const float*)d_in[5];
    const float* vp2_g   = (const float*)d_in[6];
    const float* vp2_b   = (const float*)d_in[7];
    const float* dw_w    = (const float*)d_in[8];
    const float* dw_g    = (const float*)d_in[9];
    const float* dw_b    = (const float*)d_in[10];
    const float* pw1_w   = (const float*)d_in[11];
    const float* pw1_g   = (const float*)d_in[12];
    const float* pw1_b   = (const float*)d_in[13];
    const float* pw2_w   = (const float*)d_in[14];
    const float* out_g   = (const float*)d_in[15];
    const float* out_b   = (const float*)d_in[16];
    const float* rz_attn = (const float*)d_in[17];
    const float* rz_ffn  = (const float*)d_in[18];
    const float* es      = (const float*)d_in[19];
    float* out = (float*)d_out;

    char* ws = (char*)d_ws;
    u16*   xt   = (u16*)(ws + 0);            // 65536x384 bf16 (z2 aliases from 0)
    u16*   att  = (u16*)(ws + 50331648);     // 65536x192 bf16
    u16*   z2   = (u16*)(ws + 0);            // 65536x1536 bf16 (xt+att dead by then)
    u16*   proj = (u16*)(ws + 201326592);    // 65536x640 bf16
    u16*   z1   = proj;                      // 65536x384 (proj dead)
    u16*   yt   = (u16*)(ws + 285212672);    // 65536x384 bf16
    u16*   w1p  = (u16*)(ws + 335753216);    // 640x384 bf16
    u16*   w2   = (u16*)(ws + 336244736);    // 384x192
    u16*   w3   = (u16*)(ws + 336392192);    // 1536x384
    u16*   w4   = (u16*)(ws + 337571840);    // 384x1536
    float* gp   = (float*)(ws + 338751488);  // 4x640 fp32
    float2* dwp = (float2*)(ws + 338761728); // 25x192 float2 (transposed)
    float* ktvp = (float*)(ws + 338800128);  // 192x4x272 fp32 partials

    prep<<<5885, 256, 0, stream>>>(proj_w, proj_g, proj_b, vp2_w, pw1_w, pw2_w,
                                   dw_w, w1p, w2, w3, w4, gp, dwp);
    transpose_x<<<dim3(16, 64, 6), 256, 0, stream>>>(x, xt);
    gemm_nhwc<1, 4, 4, 0><<<2560, 256, 0, stream>>>(xt, w1p, proj, 384, 640, 5,
        gp, gp + 640, gp + 1280, gp + 1920, nullptr, es, rnd);
    attn_ktv<<<dim3(192, 4), 256, 0, stream>>>(proj, ktvp);
    attn_apply<<<dim3(192, 16), 256, 0, stream>>>(proj, ktvp, att);
    gemm_nhwc<2, 8, 4, 0><<<768, 256, 0, stream>>>(att, w2, yt, 192, 384, 3,
        vp2_g, vp2_b, nullptr, nullptr, xt, rz_attn, nullptr);
    dwconv<<<dim3(64, 16), 192, 0, stream>>>(yt, dwp, dw_g, dw_b, z1);
    gemm_nhwc<3, 4, 8, 0><<<3072, 256, 0, stream>>>(z1, w3, z2, 384, 1536, 6,
        pw1_g, pw1_b, nullptr, nullptr, nullptr, nullptr, nullptr);
    // fused: gemm<4> writes fp32 NCHW output directly (transpose_out deleted)
    gemm_nhwc<4, 8, 4, 1><<<768, 256, 0, stream>>>(z2, w4, (u16*)out, 1536, 384, 3,
        out_g, out_b, nullptr, nullptr, yt, rz_ffn, nullptr);
}